// Round 1
// 794.021 us; speedup vs baseline: 1.0924x; 1.0924x over previous
//
#include <hip/hip_runtime.h>
#include <hip/hip_bf16.h>
#include <cstdint>

// GaussMemoryStep: everything reduced to bf16 MFMA GEMMs.
// F[n,j<256]=cos(2pi(j+1)n/V), F[n,256+j]=-sin(2pi(j+1)n/V);  irfft == @ (2/V)F^T.

typedef unsigned short u16;
typedef short short8 __attribute__((ext_vector_type(8)));
typedef float f32x4 __attribute__((ext_vector_type(4)));
typedef float f4 __attribute__((ext_vector_type(4)));

__device__ __forceinline__ u16 f2bf(float f) {
  union { float f; unsigned u; } v; v.f = f;
  unsigned u = v.u;
  u += 0x7fffu + ((u >> 16) & 1u);   // round-to-nearest-even
  return (u16)(u >> 16);
}

__device__ __forceinline__ void gload_lds16(const void* g, void* l) {
  __builtin_amdgcn_global_load_lds(
      (const __attribute__((address_space(1))) void*)g,
      (__attribute__((address_space(3))) void*)l, 16, 0, 0);
}

// ---------------------------------------------------------------------------
// G1 dedicated kernel: P[z] = x[:, z*4096:(z+1)*4096] @ Ft[:, z*4096:...]^T
// A fp32 [8192][8192], B bf16 [512][8192] (row-major [N][K]), P fp32 [2][8192][512].
// Split-K=2 (grid 512 blocks -> 2 blocks/CU), 1-deep pipeline (reg-prefetch A,
// double-buffered global_load_lds B), XCD-chunked swizzle so the 4 column-
// blocks sharing an A-panel colocate on one XCD's L2.
// ---------------------------------------------------------------------------
__global__ __launch_bounds__(256, 2)
void gemm_g1(const float* __restrict__ A, const u16* __restrict__ B,
             float* __restrict__ P)
{
  constexpr int NN = 512, KK = 8192, KC = 4096;
  constexpr int NT = KC / 32;   // 128 K-iterations per block

  __shared__ u16 As[2][128 * 32] __attribute__((aligned(16)));
  __shared__ u16 Bs[2][128 * 32] __attribute__((aligned(16)));

  const int tid  = threadIdx.x;
  const int wave = tid >> 6, lane = tid & 63;
  const int quad = lane >> 4, l15 = lane & 15;
  const int wm = wave >> 1, wn = wave & 1;

  // XCD-chunked bijective swizzle: xcd = lid%8 owns natural ids [xcd*64, xcd*64+64)
  const int lid = blockIdx.x;                 // 0..511
  const int nat = (lid & 7) * 64 + (lid >> 3);
  const int y = nat >> 3, rem = nat & 7;
  const int x = rem & 3, z = rem >> 2;        // y: M-panel, x: N-panel, z: K-chunk
  const int m0 = y * 128, n0 = x * 128, k00 = z * KC;

  // B global_load_lds geometry (LDS linear, lane*16B)
  const int loff0 = wave * 2048 + lane * 16;
  const int loff1 = loff0 + 1024;
  const int row0s = loff0 >> 6, kof0 = (loff0 & 63) >> 1;
  const int row1s = loff1 >> 6, kof1 = (loff1 & 63) >> 1;
  const u16* Bp0 = B + (size_t)(n0 + row0s) * KK + k00 + kof0;
  const u16* Bp1 = B + (size_t)(n0 + row1s) * KK + k00 + kof1;

  // A (fp32) load geometry: 2 threads per row, 16 consecutive floats each
  const int arow = tid >> 1, ahalf = tid & 1;
  const float* Ap = A + (size_t)(m0 + arow) * KK + k00 + ahalf * 16;
  uint4* As_dst0 = (uint4*)&As[0][arow * 32 + ahalf * 16];
  uint4* As_dst1 = (uint4*)&As[1][arow * 32 + ahalf * 16];

  f4 p0, p1, p2, p3;

  // prologue: tile 0
  p0 = ((const f4*)Ap)[0]; p1 = ((const f4*)Ap)[1];
  p2 = ((const f4*)Ap)[2]; p3 = ((const f4*)Ap)[3];
  gload_lds16(Bp0, (char*)Bs[0] + loff0);
  gload_lds16(Bp1, (char*)Bs[0] + loff1);
  {
    union { u16 h[16]; uint4 q[2]; } pk;
    #pragma unroll
    for (int e = 0; e < 4; ++e) {
      pk.h[e]      = f2bf(p0[e]);
      pk.h[4 + e]  = f2bf(p1[e]);
      pk.h[8 + e]  = f2bf(p2[e]);
      pk.h[12 + e] = f2bf(p3[e]);
    }
    As_dst0[0] = pk.q[0]; As_dst0[1] = pk.q[1];
  }
  __syncthreads();

  f32x4 acc[4][4] = {};

#define G1_COMPUTE(CUR)                                                          \
  {                                                                              \
    short8 a[4], b[4];                                                           \
    _Pragma("unroll")                                                            \
    for (int i = 0; i < 4; ++i)                                                  \
      a[i] = *(const short8*)&As[CUR][(wm * 64 + i * 16 + l15) * 32 + quad * 8]; \
    _Pragma("unroll")                                                            \
    for (int j = 0; j < 4; ++j)                                                  \
      b[j] = *(const short8*)&Bs[CUR][(wn * 64 + j * 16 + l15) * 32 + quad * 8]; \
    _Pragma("unroll")                                                            \
    for (int i = 0; i < 4; ++i)                                                  \
      _Pragma("unroll")                                                          \
      for (int j = 0; j < 4; ++j)                                                \
        acc[i][j] = __builtin_amdgcn_mfma_f32_16x16x32_bf16(a[i], b[j], acc[i][j], 0, 0, 0); \
  }

  for (int t = 0; t < NT - 1; ++t) {
    const int cur = t & 1, nxt = cur ^ 1;
    // prefetch tile t+1: A into regs first (so waiting on them leaves B in flight)
    const float* An = Ap + (t + 1) * 32;
    p0 = ((const f4*)An)[0]; p1 = ((const f4*)An)[1];
    p2 = ((const f4*)An)[2]; p3 = ((const f4*)An)[3];
    gload_lds16(Bp0 + (t + 1) * 32, (char*)Bs[nxt] + loff0);
    gload_lds16(Bp1 + (t + 1) * 32, (char*)Bs[nxt] + loff1);

    G1_COMPUTE(cur);

    // convert + stage A tile t+1 (latency of An loads hidden by MFMAs above)
    {
      union { u16 h[16]; uint4 q[2]; } pk;
      #pragma unroll
      for (int e = 0; e < 4; ++e) {
        pk.h[e]      = f2bf(p0[e]);
        pk.h[4 + e]  = f2bf(p1[e]);
        pk.h[8 + e]  = f2bf(p2[e]);
        pk.h[12 + e] = f2bf(p3[e]);
      }
      uint4* dst = nxt ? As_dst1 : As_dst0;
      dst[0] = pk.q[0]; dst[1] = pk.q[1];
    }
    __syncthreads();
  }

  G1_COMPUTE((NT - 1) & 1);
#undef G1_COMPUTE

  // epilogue: fp32 partials
  float* Pz = P + (size_t)z * (8192L * 512);
  #pragma unroll
  for (int i = 0; i < 4; ++i) {
    #pragma unroll
    for (int j = 0; j < 4; ++j) {
      const int rb = m0 + wm * 64 + i * 16 + quad * 4;
      const int cc = n0 + wn * 64 + j * 16 + l15;
      #pragma unroll
      for (int r = 0; r < 4; ++r)
        Pz[(size_t)(rb + r) * NN + cc] = acc[i][j][r];
    }
  }
}

// Xri = bf16(P[0] + P[1]) ; 4 floats per thread, vectorized
__global__ void reduce_cast(const float* __restrict__ P, u16* __restrict__ Xri) {
  const int i = blockIdx.x * 256 + threadIdx.x;     // 1M float4s
  const f4 a = ((const f4*)P)[i];
  const f4 b = ((const f4*)(P + 8192L * 512))[i];
  union { u16 h[4]; uint2 q; } pk;
  #pragma unroll
  for (int r = 0; r < 4; ++r) pk.h[r] = f2bf(a[r] + b[r]);
  ((uint2*)Xri)[i] = pk.q;
}

// ---------------------------------------------------------------------------
// General GEMM template (unchanged from baseline)
// C[m,n] = sum_k A[m,k] * B[n,k]   (B given transposed, [N][K] row-major)
// ---------------------------------------------------------------------------
template<int EPI, bool AF32>
__global__ __launch_bounds__(256, 2)
void gemm_bt(const void* __restrict__ Av, const u16* __restrict__ B,
             void* __restrict__ Cv, int M, int N, int K,
             long sA, long sB, long sC,
             const float* __restrict__ scal, float alpha)
{
  __shared__ u16 As[128 * 32] __attribute__((aligned(16)));
  __shared__ u16 Bs[128 * 32] __attribute__((aligned(16)));

  const int tid  = threadIdx.x;
  const int wave = tid >> 6, lane = tid & 63;
  const int quad = lane >> 4, l15 = lane & 15;
  const int wm = wave >> 1, wn = wave & 1;
  const int m0 = blockIdx.y * 128, n0 = blockIdx.x * 128;
  const int z  = blockIdx.z;

  const u16*   Ab = (const u16*)Av + (size_t)z * sA;
  const float* Af = (const float*)Av + (size_t)z * sA;
  const u16*   Bb = B + (size_t)z * sB;

  f32x4 acc[4][4] = {};

  const int loff0 = wave * 2048 + lane * 16;
  const int loff1 = loff0 + 1024;
  const int row0s = loff0 >> 6, kof0 = (loff0 & 63) >> 1;
  const int row1s = loff1 >> 6, kof1 = (loff1 & 63) >> 1;

  for (int k0 = 0; k0 < K; k0 += 32) {
    __syncthreads();
    if (AF32) {
      const int row = tid >> 1, half = tid & 1;
      const float* ar = Af + (size_t)(m0 + row) * K + k0 + half * 16;
      f4 p0 = *(const f4*)(ar);
      f4 p1 = *(const f4*)(ar + 4);
      f4 p2 = *(const f4*)(ar + 8);
      f4 p3 = *(const f4*)(ar + 12);
      union { u16 h[16]; uint4 q[2]; } pk;
      #pragma unroll
      for (int e = 0; e < 4; ++e) {
        pk.h[e]      = f2bf(p0[e]);
        pk.h[4 + e]  = f2bf(p1[e]);
        pk.h[8 + e]  = f2bf(p2[e]);
        pk.h[12 + e] = f2bf(p3[e]);
      }
      uint4* dst = (uint4*)&As[row * 32 + half * 16];
      dst[0] = pk.q[0]; dst[1] = pk.q[1];
    } else {
      gload_lds16(Ab + (size_t)(m0 + row0s) * K + k0 + kof0, (char*)As + loff0);
      gload_lds16(Ab + (size_t)(m0 + row1s) * K + k0 + kof1, (char*)As + loff1);
    }
    gload_lds16(Bb + (size_t)(n0 + row0s) * K + k0 + kof0, (char*)Bs + loff0);
    gload_lds16(Bb + (size_t)(n0 + row1s) * K + k0 + kof1, (char*)Bs + loff1);
    __syncthreads();

    short8 a[4], b[4];
    #pragma unroll
    for (int i = 0; i < 4; ++i)
      a[i] = *(const short8*)&As[(wm * 64 + i * 16 + l15) * 32 + quad * 8];
    #pragma unroll
    for (int j = 0; j < 4; ++j)
      b[j] = *(const short8*)&Bs[(wn * 64 + j * 16 + l15) * 32 + quad * 8];
    #pragma unroll
    for (int i = 0; i < 4; ++i)
      #pragma unroll
      for (int j = 0; j < 4; ++j)
        acc[i][j] = __builtin_amdgcn_mfma_f32_16x16x32_bf16(a[i], b[j], acc[i][j], 0, 0, 0);
  }

  float dec_l2 = 0.f, oscale = 1.f;
  if (EPI == 3) {
    float logit = *scal;
    float dec = 1.f / (1.f + expf(-logit));
    dec_l2 = log2f(dec);
  }
  if (EPI == 4) oscale = *scal;

  #pragma unroll
  for (int i = 0; i < 4; ++i) {
    #pragma unroll
    for (int j = 0; j < 4; ++j) {
      f32x4 v = acc[i][j];
      const int rb = m0 + wm * 64 + i * 16 + quad * 4;
      const int cc = n0 + wn * 64 + j * 16 + l15;
      if (EPI == 0) {
        u16* C = (u16*)Cv + (size_t)z * sC;
        #pragma unroll
        for (int r = 0; r < 4; ++r)
          C[(size_t)(rb + r) * N + cc] = f2bf(v[r] * alpha);
      } else if (EPI == 2) {
        u16* C = (u16*)Cv;
        const int bb = rb >> 11, ml = rb & 2047;
        union { u16 h[4]; uint2 q; } pk;
        #pragma unroll
        for (int r = 0; r < 4; ++r) pk.h[r] = f2bf(v[r]);
        *(uint2*)&C[((size_t)(bb << 8) + cc) * 2048 + ml] = pk.q;
      } else if (EPI == 3) {
        u16* C = (u16*)Cv + (size_t)z * sC;
        #pragma unroll
        for (int r = 0; r < 4; ++r) {
          const int d = cc - (rb + r);            // s - t
          float w = (d > 0) ? exp2f(dec_l2 * (float)(d - 1)) : 0.f;
          C[(size_t)(rb + r) * N + cc] = f2bf(v[r] * w);
        }
      } else if (EPI == 4) {
        float* C = (float*)Cv;
        #pragma unroll
        for (int r = 0; r < 4; ++r)
          C[(size_t)(rb + r) * N + cc] = v[r] * oscale;
      }
    }
  }
}

// F tables: exact integer phase reduction (n*k mod 8192) before trig.
__global__ void genF_row(u16* Fm) {           // Fm [8192][512], coalesced in j
  int idx = blockIdx.x * 256 + threadIdx.x;
  int n = idx >> 9, j = idx & 511;
  int k = (j & 255) + 1;
  int ph = (n * k) & 8191;
  float ang = (float)ph * 7.66990393942820795e-4f;  // 2*pi/8192
  float s, c; sincosf(ang, &s, &c);
  Fm[idx] = f2bf(j < 256 ? c : -s);
}
__global__ void genF_col(u16* Ft) {           // Ft [512][8192], coalesced in n
  int idx = blockIdx.x * 256 + threadIdx.x;
  int j = idx >> 13, n = idx & 8191;
  int k = (j & 255) + 1;
  int ph = (n * k) & 8191;
  float ang = (float)ph * 7.66990393942820795e-4f;
  float s, c; sincosf(ang, &s, &c);
  Ft[idx] = f2bf(j < 256 ? c : -s);
}

__global__ void cast_w4(const float* a, const float* b, const float* c, const float* d,
                        u16* oa, u16* ob, u16* oc, u16* od) {
  int i = blockIdx.x * 256 + threadIdx.x;     // 131072 each
  oa[i] = f2bf(a[i]); ob[i] = f2bf(b[i]); oc[i] = f2bf(c[i]); od[i] = f2bf(d[i]);
}

extern "C" void kernel_launch(void* const* d_in, const int* in_sizes, int n_in,
                              void* d_out, int out_size, void* d_ws, size_t ws_size,
                              hipStream_t stream)
{
  const float* x  = (const float*)d_in[0];
  const float* qw = (const float*)d_in[1];
  const float* kw = (const float*)d_in[2];
  const float* vw = (const float*)d_in[3];
  const float* ow = (const float*)d_in[4];
  const float* dl = (const float*)d_in[5];   // decay_logit
  const float* os = (const float*)d_in[6];   // out_scale
  float* out = (float*)d_out;

  char* W = (char*)d_ws;
  const size_t MB = 1024 * 1024;
  u16* Fm  = (u16*)(W);             // [8192][512]   8 MB
  u16* Ft  = (u16*)(W + 8 * MB);    // [512][8192]   8 MB
  u16* Xri = (u16*)(W + 16 * MB);   // [8192][512]   8 MB
  u16* Qb  = (u16*)(W + 24 * MB);   // [8192][256]   4 MB
  u16* Kb  = (u16*)(W + 28 * MB);   // [8192][256]   4 MB
  u16* Vt  = (u16*)(W + 32 * MB);   // [4][256][2048] 4 MB
  u16* Wot = (u16*)(W + 36 * MB);   // [8192][256]   4 MB
  u16* S   = (u16*)(W + 40 * MB);   // [4][2048][2048] 32 MB (S aliases P; P dead before G4)
  float* P = (float*)(W + 40 * MB); // [2][8192][512] fp32 32 MB split-K partials
  u16* R   = (u16*)(W + 72 * MB);   // [8192][256]   4 MB
  u16* qwb = (u16*)(W + 76 * MB);   // 4 x 256 KB
  u16* kwb = qwb + 131072;
  u16* vwb = kwb + 131072;
  u16* owb = vwb + 131072;

  genF_row<<<8192 * 512 / 256, 256, 0, stream>>>(Fm);
  genF_col<<<8192 * 512 / 256, 256, 0, stream>>>(Ft);
  cast_w4<<<131072 / 256, 256, 0, stream>>>(qw, kw, vw, ow, qwb, kwb, vwb, owb);

  // G1: Xri = x @ F           M=8192 N=512 K=8192  (A is fp32)
  // split-K=2 pipelined kernel -> fp32 partials P, then reduce+cast to bf16
  gemm_g1<<<512, 256, 0, stream>>>(x, Ft, P);
  reduce_cast<<<4096, 256, 0, stream>>>(P, Xri);

  // G2: q, k, v = Xri @ w^T   M=8192 N=256 K=512   (v written transposed)
  gemm_bt<0, false><<<dim3(2, 64, 1), 256, 0, stream>>>(Xri, qwb, Qb, 8192, 256, 512, 0, 0, 0, nullptr, 1.f);
  gemm_bt<0, false><<<dim3(2, 64, 1), 256, 0, stream>>>(Xri, kwb, Kb, 8192, 256, 512, 0, 0, 0, nullptr, 1.f);
  gemm_bt<2, false><<<dim3(2, 64, 1), 256, 0, stream>>>(Xri, vwb, Vt, 8192, 256, 512, 0, 0, 0, nullptr, 1.f);
  // G3: Wot = (2/V) * F @ o_w^T   M=8192 N=256 K=512
  gemm_bt<0, false><<<dim3(2, 64, 1), 256, 0, stream>>>(Fm, owb, Wot, 8192, 256, 512, 0, 0, 0, nullptr, 2.f / 8192.f);
  // G4: S[b] = (q k^T) .* weight   M=N=2048 K=256, z=batch
  gemm_bt<3, false><<<dim3(16, 16, 4), 256, 0, stream>>>(Qb, Kb, S, 2048, 2048, 256,
                                                         2048L * 256, 2048L * 256, 2048L * 2048, dl, 1.f);
  // G5: R[b] = S[b] @ v[b]    M=2048 N=256 K=2048
  gemm_bt<0, false><<<dim3(2, 16, 4), 256, 0, stream>>>(S, Vt, R, 2048, 256, 2048,
                                                        2048L * 2048, 256L * 2048, 2048L * 256, nullptr, 1.f);
  // G6: out = (R @ Wot^T) * out_scale   M=8192 N=8192 K=256, fp32 out
  gemm_bt<4, false><<<dim3(64, 64, 1), 256, 0, stream>>>(R, Wot, out, 8192, 8192, 256, 0, 0, 0, os, 1.f);
}

// Round 2
// 716.097 us; speedup vs baseline: 1.2113x; 1.1088x over previous
//
#include <hip/hip_runtime.h>
#include <hip/hip_bf16.h>
#include <cstdint>

// GaussMemoryStep: everything reduced to bf16 MFMA GEMMs.
// F[n,j<256]=cos(2pi(j+1)n/V), F[n,256+j]=-sin(2pi(j+1)n/V);  irfft == @ (2/V)F^T.

typedef unsigned short u16;
typedef short short8 __attribute__((ext_vector_type(8)));
typedef float f32x4 __attribute__((ext_vector_type(4)));
typedef float f4 __attribute__((ext_vector_type(4)));

__device__ __forceinline__ u16 f2bf(float f) {
  union { float f; unsigned u; } v; v.f = f;
  unsigned u = v.u;
  u += 0x7fffu + ((u >> 16) & 1u);   // round-to-nearest-even
  return (u16)(u >> 16);
}

__device__ __forceinline__ uint2 pack_bf4(f4 v) {
  union { u16 h[4]; uint2 q; } pk;
  pk.h[0] = f2bf(v[0]); pk.h[1] = f2bf(v[1]);
  pk.h[2] = f2bf(v[2]); pk.h[3] = f2bf(v[3]);
  return pk.q;
}

__device__ __forceinline__ void gload_lds16(const void* g, void* l) {
  __builtin_amdgcn_global_load_lds(
      (const __attribute__((address_space(1))) void*)g,
      (__attribute__((address_space(3))) void*)l, 16, 0, 0);
}

// ---------------------------------------------------------------------------
// G1 dedicated kernel: P[z] = x[:, z*4096:(z+1)*4096] @ Ft[:, z*4096:...]^T
// A fp32 [8192][8192], B bf16 [512][8192] ([N][K] row-major), P fp32 [2][8192][512].
// Split-K=2, 1-deep pipeline, XCD-chunked swizzle.
// A-path: COALESCED loads (inst g: thread t -> row g*32+(t>>3), 16B at col (t&7)*4)
// and conflict-free ds_write_b64 (lanes sweep all 32 banks uniformly).
// ---------------------------------------------------------------------------
__global__ __launch_bounds__(256, 2)
void gemm_g1(const float* __restrict__ A, const u16* __restrict__ B,
             float* __restrict__ P)
{
  constexpr int NN = 512, KK = 8192, KC = 4096;
  constexpr int NT = KC / 32;   // 128 K-iterations per block

  __shared__ u16 As[2][128 * 32] __attribute__((aligned(16)));
  __shared__ u16 Bs[2][128 * 32] __attribute__((aligned(16)));

  const int tid  = threadIdx.x;
  const int wave = tid >> 6, lane = tid & 63;
  const int quad = lane >> 4, l15 = lane & 15;
  const int wm = wave >> 1, wn = wave & 1;

  // XCD-chunked bijective swizzle: xcd = lid%8 owns natural ids [xcd*64, xcd*64+64)
  const int lid = blockIdx.x;                 // 0..511
  const int nat = (lid & 7) * 64 + (lid >> 3);
  const int y = nat >> 3, rem = nat & 7;
  const int x = rem & 3, z = rem >> 2;        // y: M-panel, x: N-panel, z: K-chunk
  const int m0 = y * 128, n0 = x * 128, k00 = z * KC;

  // B global_load_lds geometry (LDS linear, lane*16B)
  const int loff0 = wave * 2048 + lane * 16;
  const int loff1 = loff0 + 1024;
  const int row0s = loff0 >> 6, kof0 = (loff0 & 63) >> 1;
  const int row1s = loff1 >> 6, kof1 = (loff1 & 63) >> 1;
  const u16* Bp0 = B + (size_t)(n0 + row0s) * KK + k00 + kof0;
  const u16* Bp1 = B + (size_t)(n0 + row1s) * KK + k00 + kof1;

  // A (fp32) coalesced geometry: inst g covers rows [g*32, g*32+32),
  // thread t -> row g*32 + (t>>3), float-col (t&7)*4 (16B), per-wave contiguous.
  const int arow8 = tid >> 3;          // 0..31
  const int acol  = (tid & 7) * 4;     // 0,4,...,28
  const float* Ap = A + (size_t)(m0 + arow8) * KK + k00 + acol;
  // LDS u16 index for (g, buf): (g*32 + arow8)*32 + acol

  f4 pv[4];

  // prologue: tile 0
  #pragma unroll
  for (int g = 0; g < 4; ++g)
    pv[g] = *(const f4*)(Ap + (size_t)g * 32 * KK);
  gload_lds16(Bp0, (char*)Bs[0] + loff0);
  gload_lds16(Bp1, (char*)Bs[0] + loff1);
  #pragma unroll
  for (int g = 0; g < 4; ++g)
    *(uint2*)&As[0][(g * 32 + arow8) * 32 + acol] = pack_bf4(pv[g]);
  __syncthreads();

  f32x4 acc[4][4] = {};

#define G1_COMPUTE(CUR)                                                          \
  {                                                                              \
    short8 a[4], b[4];                                                           \
    _Pragma("unroll")                                                            \
    for (int i = 0; i < 4; ++i)                                                  \
      a[i] = *(const short8*)&As[CUR][(wm * 64 + i * 16 + l15) * 32 + quad * 8]; \
    _Pragma("unroll")                                                            \
    for (int j = 0; j < 4; ++j)                                                  \
      b[j] = *(const short8*)&Bs[CUR][(wn * 64 + j * 16 + l15) * 32 + quad * 8]; \
    _Pragma("unroll")                                                            \
    for (int i = 0; i < 4; ++i)                                                  \
      _Pragma("unroll")                                                          \
      for (int j = 0; j < 4; ++j)                                                \
        acc[i][j] = __builtin_amdgcn_mfma_f32_16x16x32_bf16(a[i], b[j], acc[i][j], 0, 0, 0); \
  }

  for (int t = 0; t < NT - 1; ++t) {
    const int cur = t & 1, nxt = cur ^ 1;
    // prefetch tile t+1: A into regs first (so the convert waits only on A,
    // leaving the B gload_lds in flight until the barrier)
    #pragma unroll
    for (int g = 0; g < 4; ++g)
      pv[g] = *(const f4*)(Ap + (size_t)g * 32 * KK + (t + 1) * 32);
    gload_lds16(Bp0 + (t + 1) * 32, (char*)Bs[nxt] + loff0);
    gload_lds16(Bp1 + (t + 1) * 32, (char*)Bs[nxt] + loff1);

    G1_COMPUTE(cur);

    // convert + stage A tile t+1 (A-load latency hidden by MFMAs above)
    #pragma unroll
    for (int g = 0; g < 4; ++g)
      *(uint2*)&As[nxt][(g * 32 + arow8) * 32 + acol] = pack_bf4(pv[g]);
    __syncthreads();
  }

  G1_COMPUTE((NT - 1) & 1);
#undef G1_COMPUTE

  // epilogue: fp32 partials
  float* Pz = P + (size_t)z * (8192L * 512);
  #pragma unroll
  for (int i = 0; i < 4; ++i) {
    #pragma unroll
    for (int j = 0; j < 4; ++j) {
      const int rb = m0 + wm * 64 + i * 16 + quad * 4;
      const int cc = n0 + wn * 64 + j * 16 + l15;
      #pragma unroll
      for (int r = 0; r < 4; ++r)
        Pz[(size_t)(rb + r) * NN + cc] = acc[i][j][r];
    }
  }
}

// Xri = bf16(P[0] + P[1]) ; 4 floats per thread, vectorized
__global__ void reduce_cast(const float* __restrict__ P, u16* __restrict__ Xri) {
  const int i = blockIdx.x * 256 + threadIdx.x;     // 1M float4s
  const f4 a = ((const f4*)P)[i];
  const f4 b = ((const f4*)(P + 8192L * 512))[i];
  union { u16 h[4]; uint2 q; } pk;
  #pragma unroll
  for (int r = 0; r < 4; ++r) pk.h[r] = f2bf(a[r] + b[r]);
  ((uint2*)Xri)[i] = pk.q;
}

// ---------------------------------------------------------------------------
// Merged Q/K/V/Wot kernel: four M=8192,N=256,K=512 bf16 GEMMs as z-slices.
// z=0: Qb = Xri @ qw^T;  z=1: Kb = Xri @ kw^T;
// z=2: Vt = (Xri @ vw^T) transposed;  z=3: Wot = (2/V) * Fm @ ow^T.
// ---------------------------------------------------------------------------
__global__ __launch_bounds__(256, 2)
void gemm_qkvw(const u16* __restrict__ Xri, const u16* __restrict__ Fm,
               const u16* __restrict__ qwb, const u16* __restrict__ kwb,
               const u16* __restrict__ vwb, const u16* __restrict__ owb,
               u16* __restrict__ Qb, u16* __restrict__ Kb,
               u16* __restrict__ Vt, u16* __restrict__ Wot)
{
  constexpr int N = 256, K = 512;
  __shared__ u16 As[128 * 32] __attribute__((aligned(16)));
  __shared__ u16 Bs[128 * 32] __attribute__((aligned(16)));

  const int tid  = threadIdx.x;
  const int wave = tid >> 6, lane = tid & 63;
  const int quad = lane >> 4, l15 = lane & 15;
  const int wm = wave >> 1, wn = wave & 1;
  const int m0 = blockIdx.y * 128, n0 = blockIdx.x * 128;
  const int z  = blockIdx.z;

  const u16* Ab = (z == 3) ? Fm : Xri;
  const u16* Bb = (z == 0) ? qwb : (z == 1) ? kwb : (z == 2) ? vwb : owb;
  const float alpha = (z == 3) ? (2.f / 8192.f) : 1.f;

  f32x4 acc[4][4] = {};

  const int loff0 = wave * 2048 + lane * 16;
  const int loff1 = loff0 + 1024;
  const int row0s = loff0 >> 6, kof0 = (loff0 & 63) >> 1;
  const int row1s = loff1 >> 6, kof1 = (loff1 & 63) >> 1;

  for (int k0 = 0; k0 < K; k0 += 32) {
    __syncthreads();
    gload_lds16(Ab + (size_t)(m0 + row0s) * K + k0 + kof0, (char*)As + loff0);
    gload_lds16(Ab + (size_t)(m0 + row1s) * K + k0 + kof1, (char*)As + loff1);
    gload_lds16(Bb + (size_t)(n0 + row0s) * K + k0 + kof0, (char*)Bs + loff0);
    gload_lds16(Bb + (size_t)(n0 + row1s) * K + k0 + kof1, (char*)Bs + loff1);
    __syncthreads();

    short8 a[4], b[4];
    #pragma unroll
    for (int i = 0; i < 4; ++i)
      a[i] = *(const short8*)&As[(wm * 64 + i * 16 + l15) * 32 + quad * 8];
    #pragma unroll
    for (int j = 0; j < 4; ++j)
      b[j] = *(const short8*)&Bs[(wn * 64 + j * 16 + l15) * 32 + quad * 8];
    #pragma unroll
    for (int i = 0; i < 4; ++i)
      #pragma unroll
      for (int j = 0; j < 4; ++j)
        acc[i][j] = __builtin_amdgcn_mfma_f32_16x16x32_bf16(a[i], b[j], acc[i][j], 0, 0, 0);
  }

  #pragma unroll
  for (int i = 0; i < 4; ++i) {
    #pragma unroll
    for (int j = 0; j < 4; ++j) {
      f32x4 v = acc[i][j];
      const int rb = m0 + wm * 64 + i * 16 + quad * 4;
      const int cc = n0 + wn * 64 + j * 16 + l15;
      if (z == 2) {
        // Vt[b][cc][t],  t = rb&2047, b = rb>>11, ld 2048
        const int bb = rb >> 11, ml = rb & 2047;
        union { u16 h[4]; uint2 q; } pk;
        #pragma unroll
        for (int r = 0; r < 4; ++r) pk.h[r] = f2bf(v[r]);
        *(uint2*)&Vt[((size_t)(bb << 8) + cc) * 2048 + ml] = pk.q;
      } else {
        u16* C = (z == 0) ? Qb : (z == 1) ? Kb : Wot;
        #pragma unroll
        for (int r = 0; r < 4; ++r)
          C[(size_t)(rb + r) * N + cc] = f2bf(v[r] * alpha);
      }
    }
  }
}

// ---------------------------------------------------------------------------
// General GEMM template (G4, G5, G6)
// C[m,n] = sum_k A[m,k] * B[n,k]   (B given transposed, [N][K] row-major)
// ---------------------------------------------------------------------------
template<int EPI, bool AF32>
__global__ __launch_bounds__(256, 2)
void gemm_bt(const void* __restrict__ Av, const u16* __restrict__ B,
             void* __restrict__ Cv, int M, int N, int K,
             long sA, long sB, long sC,
             const float* __restrict__ scal, float alpha)
{
  __shared__ u16 As[128 * 32] __attribute__((aligned(16)));
  __shared__ u16 Bs[128 * 32] __attribute__((aligned(16)));

  const int tid  = threadIdx.x;
  const int wave = tid >> 6, lane = tid & 63;
  const int quad = lane >> 4, l15 = lane & 15;
  const int wm = wave >> 1, wn = wave & 1;
  const int m0 = blockIdx.y * 128, n0 = blockIdx.x * 128;
  const int z  = blockIdx.z;

  const u16*   Ab = (const u16*)Av + (size_t)z * sA;
  const float* Af = (const float*)Av + (size_t)z * sA;
  const u16*   Bb = B + (size_t)z * sB;

  f32x4 acc[4][4] = {};

  const int loff0 = wave * 2048 + lane * 16;
  const int loff1 = loff0 + 1024;
  const int row0s = loff0 >> 6, kof0 = (loff0 & 63) >> 1;
  const int row1s = loff1 >> 6, kof1 = (loff1 & 63) >> 1;

  for (int k0 = 0; k0 < K; k0 += 32) {
    __syncthreads();
    if (AF32) {
      const int row = tid >> 1, half = tid & 1;
      const float* ar = Af + (size_t)(m0 + row) * K + k0 + half * 16;
      f4 p0 = *(const f4*)(ar);
      f4 p1 = *(const f4*)(ar + 4);
      f4 p2 = *(const f4*)(ar + 8);
      f4 p3 = *(const f4*)(ar + 12);
      union { u16 h[16]; uint4 q[2]; } pk;
      #pragma unroll
      for (int e = 0; e < 4; ++e) {
        pk.h[e]      = f2bf(p0[e]);
        pk.h[4 + e]  = f2bf(p1[e]);
        pk.h[8 + e]  = f2bf(p2[e]);
        pk.h[12 + e] = f2bf(p3[e]);
      }
      uint4* dst = (uint4*)&As[row * 32 + half * 16];
      dst[0] = pk.q[0]; dst[1] = pk.q[1];
    } else {
      gload_lds16(Ab + (size_t)(m0 + row0s) * K + k0 + kof0, (char*)As + loff0);
      gload_lds16(Ab + (size_t)(m0 + row1s) * K + k0 + kof1, (char*)As + loff1);
    }
    gload_lds16(Bb + (size_t)(n0 + row0s) * K + k0 + kof0, (char*)Bs + loff0);
    gload_lds16(Bb + (size_t)(n0 + row1s) * K + k0 + kof1, (char*)Bs + loff1);
    __syncthreads();

    short8 a[4], b[4];
    #pragma unroll
    for (int i = 0; i < 4; ++i)
      a[i] = *(const short8*)&As[(wm * 64 + i * 16 + l15) * 32 + quad * 8];
    #pragma unroll
    for (int j = 0; j < 4; ++j)
      b[j] = *(const short8*)&Bs[(wn * 64 + j * 16 + l15) * 32 + quad * 8];
    #pragma unroll
    for (int i = 0; i < 4; ++i)
      #pragma unroll
      for (int j = 0; j < 4; ++j)
        acc[i][j] = __builtin_amdgcn_mfma_f32_16x16x32_bf16(a[i], b[j], acc[i][j], 0, 0, 0);
  }

  float dec_l2 = 0.f, oscale = 1.f;
  if (EPI == 3) {
    float logit = *scal;
    float dec = 1.f / (1.f + expf(-logit));
    dec_l2 = log2f(dec);
  }
  if (EPI == 4) oscale = *scal;

  #pragma unroll
  for (int i = 0; i < 4; ++i) {
    #pragma unroll
    for (int j = 0; j < 4; ++j) {
      f32x4 v = acc[i][j];
      const int rb = m0 + wm * 64 + i * 16 + quad * 4;
      const int cc = n0 + wn * 64 + j * 16 + l15;
      if (EPI == 0) {
        u16* C = (u16*)Cv + (size_t)z * sC;
        #pragma unroll
        for (int r = 0; r < 4; ++r)
          C[(size_t)(rb + r) * N + cc] = f2bf(v[r] * alpha);
      } else if (EPI == 2) {
        u16* C = (u16*)Cv;
        const int bb = rb >> 11, ml = rb & 2047;
        union { u16 h[4]; uint2 q; } pk;
        #pragma unroll
        for (int r = 0; r < 4; ++r) pk.h[r] = f2bf(v[r]);
        *(uint2*)&C[((size_t)(bb << 8) + cc) * 2048 + ml] = pk.q;
      } else if (EPI == 3) {
        u16* C = (u16*)Cv + (size_t)z * sC;
        #pragma unroll
        for (int r = 0; r < 4; ++r) {
          const int d = cc - (rb + r);            // s - t
          float w = (d > 0) ? exp2f(dec_l2 * (float)(d - 1)) : 0.f;
          C[(size_t)(rb + r) * N + cc] = f2bf(v[r] * w);
        }
      } else if (EPI == 4) {
        float* C = (float*)Cv;
        #pragma unroll
        for (int r = 0; r < 4; ++r)
          C[(size_t)(rb + r) * N + cc] = v[r] * oscale;
      }
    }
  }
}

// F tables: exact integer phase reduction (n*k mod 8192) before trig.
__global__ void genF_row(u16* Fm) {           // Fm [8192][512], coalesced in j
  int idx = blockIdx.x * 256 + threadIdx.x;
  int n = idx >> 9, j = idx & 511;
  int k = (j & 255) + 1;
  int ph = (n * k) & 8191;
  float ang = (float)ph * 7.66990393942820795e-4f;  // 2*pi/8192
  float s, c; sincosf(ang, &s, &c);
  Fm[idx] = f2bf(j < 256 ? c : -s);
}
__global__ void genF_col(u16* Ft) {           // Ft [512][8192], coalesced in n
  int idx = blockIdx.x * 256 + threadIdx.x;
  int j = idx >> 13, n = idx & 8191;
  int k = (j & 255) + 1;
  int ph = (n * k) & 8191;
  float ang = (float)ph * 7.66990393942820795e-4f;
  float s, c; sincosf(ang, &s, &c);
  Ft[idx] = f2bf(j < 256 ? c : -s);
}

__global__ void cast_w4(const float* a, const float* b, const float* c, const float* d,
                        u16* oa, u16* ob, u16* oc, u16* od) {
  int i = blockIdx.x * 256 + threadIdx.x;     // 131072 each
  oa[i] = f2bf(a[i]); ob[i] = f2bf(b[i]); oc[i] = f2bf(c[i]); od[i] = f2bf(d[i]);
}

extern "C" void kernel_launch(void* const* d_in, const int* in_sizes, int n_in,
                              void* d_out, int out_size, void* d_ws, size_t ws_size,
                              hipStream_t stream)
{
  const float* x  = (const float*)d_in[0];
  const float* qw = (const float*)d_in[1];
  const float* kw = (const float*)d_in[2];
  const float* vw = (const float*)d_in[3];
  const float* ow = (const float*)d_in[4];
  const float* dl = (const float*)d_in[5];   // decay_logit
  const float* os = (const float*)d_in[6];   // out_scale
  float* out = (float*)d_out;

  char* W = (char*)d_ws;
  const size_t MB = 1024 * 1024;
  u16* Fm  = (u16*)(W);             // [8192][512]   8 MB
  u16* Ft  = (u16*)(W + 8 * MB);    // [512][8192]   8 MB
  u16* Xri = (u16*)(W + 16 * MB);   // [8192][512]   8 MB
  u16* Qb  = (u16*)(W + 24 * MB);   // [8192][256]   4 MB
  u16* Kb  = (u16*)(W + 28 * MB);   // [8192][256]   4 MB
  u16* Vt  = (u16*)(W + 32 * MB);   // [4][256][2048] 4 MB
  u16* Wot = (u16*)(W + 36 * MB);   // [8192][256]   4 MB
  u16* S   = (u16*)(W + 40 * MB);   // [4][2048][2048] 32 MB (S aliases P; P dead before G4)
  float* P = (float*)(W + 40 * MB); // [2][8192][512] fp32 32 MB split-K partials
  u16* R   = (u16*)(W + 72 * MB);   // [8192][256]   4 MB
  u16* qwb = (u16*)(W + 76 * MB);   // 4 x 256 KB
  u16* kwb = qwb + 131072;
  u16* vwb = kwb + 131072;
  u16* owb = vwb + 131072;

  genF_row<<<8192 * 512 / 256, 256, 0, stream>>>(Fm);
  genF_col<<<8192 * 512 / 256, 256, 0, stream>>>(Ft);
  cast_w4<<<131072 / 256, 256, 0, stream>>>(qw, kw, vw, ow, qwb, kwb, vwb, owb);

  // G1: Xri = x @ F           M=8192 N=512 K=8192  (A is fp32)
  // split-K=2 pipelined kernel -> fp32 partials P, then reduce+cast to bf16
  gemm_g1<<<512, 256, 0, stream>>>(x, Ft, P);
  reduce_cast<<<4096, 256, 0, stream>>>(P, Xri);

  // G2+G3 merged: q, k, v = Xri @ w^T ; Wot = (2/V) * Fm @ ow^T   (512 blocks)
  gemm_qkvw<<<dim3(2, 64, 4), 256, 0, stream>>>(Xri, Fm, qwb, kwb, vwb, owb,
                                                Qb, Kb, Vt, Wot);

  // G4: S[b] = (q k^T) .* weight   M=N=2048 K=256, z=batch
  gemm_bt<3, false><<<dim3(16, 16, 4), 256, 0, stream>>>(Qb, Kb, S, 2048, 2048, 256,
                                                         2048L * 256, 2048L * 256, 2048L * 2048, dl, 1.f);
  // G5: R[b] = S[b] @ v[b]    M=2048 N=256 K=2048
  gemm_bt<0, false><<<dim3(2, 16, 4), 256, 0, stream>>>(S, Vt, R, 2048, 256, 2048,
                                                        2048L * 2048, 256L * 2048, 2048L * 256, nullptr, 1.f);
  // G6: out = (R @ Wot^T) * out_scale   M=8192 N=8192 K=256, fp32 out
  gemm_bt<4, false><<<dim3(64, 64, 1), 256, 0, stream>>>(R, Wot, out, 8192, 8192, 256, 0, 0, 0, os, 1.f);
}

// Round 3
// 680.460 us; speedup vs baseline: 1.2747x; 1.0524x over previous
//
#include <hip/hip_runtime.h>
#include <hip/hip_bf16.h>
#include <cstdint>

// GaussMemoryStep: everything reduced to bf16 MFMA GEMMs.
// F[n,j<256]=cos(2pi(j+1)n/V), F[n,256+j]=-sin(2pi(j+1)n/V);  irfft == @ (2/V)F^T.

typedef unsigned short u16;
typedef short short8 __attribute__((ext_vector_type(8)));
typedef float f32x4 __attribute__((ext_vector_type(4)));
typedef float f4 __attribute__((ext_vector_type(4)));

__device__ __forceinline__ u16 f2bf(float f) {
  union { float f; unsigned u; } v; v.f = f;
  unsigned u = v.u;
  u += 0x7fffu + ((u >> 16) & 1u);   // round-to-nearest-even
  return (u16)(u >> 16);
}

__device__ __forceinline__ uint2 pack_bf4(f4 v) {
  union { u16 h[4]; uint2 q; } pk;
  pk.h[0] = f2bf(v[0]); pk.h[1] = f2bf(v[1]);
  pk.h[2] = f2bf(v[2]); pk.h[3] = f2bf(v[3]);
  return pk.q;
}

__device__ __forceinline__ void gload_lds16(const void* g, void* l) {
  __builtin_amdgcn_global_load_lds(
      (const __attribute__((address_space(1))) void*)g,
      (__attribute__((address_space(3))) void*)l, 16, 0, 0);
}

// ---------------------------------------------------------------------------
// G1 dedicated kernel: P[z] = x[:, z*4096:(z+1)*4096] @ Ft[:, z*4096:...]^T
// A fp32 [8192][8192], B bf16 [512][8192] ([N][K] row-major), P fp32 [2][8192][512].
// Split-K=2, XCD-chunked swizzle, coalesced A path.
// NEW: 2-deep pipeline with RAW s_barrier + counted vmcnt(6) (T3/T4): loads for
// tile t+2 stay in flight across barriers; __syncthreads' vmcnt(0) drain gone.
// vmcnt ledger: entry invariant = 6 outstanding {A(t+1)x4, B(t+1)x2};
// issue 6 for t+2 -> 12; convert auto-waits vmcnt(8) for A(t+1) regs;
// explicit vmcnt(6) leaves exactly {A(t+2), B(t+2)} in flight.
// ---------------------------------------------------------------------------
__global__ __launch_bounds__(256, 2)
void gemm_g1(const float* __restrict__ A, const u16* __restrict__ B,
             float* __restrict__ P)
{
  constexpr int NN = 512, KK = 8192, KC = 4096;
  constexpr int NT = KC / 32;   // 128 K-iterations per block

  __shared__ u16 As[2][128 * 32] __attribute__((aligned(16)));
  __shared__ u16 Bs[3][128 * 32] __attribute__((aligned(16)));

  const int tid  = threadIdx.x;
  const int wave = tid >> 6, lane = tid & 63;
  const int quad = lane >> 4, l15 = lane & 15;
  const int wm = wave >> 1, wn = wave & 1;

  // XCD-chunked bijective swizzle: xcd = lid%8 owns natural ids [xcd*64, xcd*64+64)
  const int lid = blockIdx.x;                 // 0..511
  const int nat = (lid & 7) * 64 + (lid >> 3);
  const int y = nat >> 3, rem = nat & 7;
  const int x = rem & 3, z = rem >> 2;        // y: M-panel, x: N-panel, z: K-chunk
  const int m0 = y * 128, n0 = x * 128, k00 = z * KC;

  // B global_load_lds geometry (LDS linear, lane*16B)
  const int loff0 = wave * 2048 + lane * 16;
  const int loff1 = loff0 + 1024;
  const int row0s = loff0 >> 6, kof0 = (loff0 & 63) >> 1;
  const int row1s = loff1 >> 6, kof1 = (loff1 & 63) >> 1;
  const u16* Bp0 = B + (size_t)(n0 + row0s) * KK + k00 + kof0;
  const u16* Bp1 = B + (size_t)(n0 + row1s) * KK + k00 + kof1;

  // A (fp32) coalesced geometry: inst g: thread t -> row g*32+(t>>3), 16B at col (t&7)*4
  const int arow8 = tid >> 3;          // 0..31
  const int acol  = (tid & 7) * 4;     // 0,4,...,28
  const float* Ap = A + (size_t)(m0 + arow8) * KK + k00 + acol;

  f4 rv0[4], rv1[4];                   // two A-prefetch stages (static roles)

#define ISSUE_A(RV, T)                                               \
  _Pragma("unroll")                                                  \
  for (int g = 0; g < 4; ++g)                                        \
    RV[g] = *(const f4*)(Ap + (size_t)g * 32 * KK + (size_t)(T) * 32);
#define ISSUE_B(T, SLOT)                                             \
  gload_lds16(Bp0 + (size_t)(T) * 32, (char*)Bs[SLOT] + loff0);      \
  gload_lds16(Bp1 + (size_t)(T) * 32, (char*)Bs[SLOT] + loff1);
#define CONVERT_A(RV, SLOT)                                          \
  _Pragma("unroll")                                                  \
  for (int g = 0; g < 4; ++g)                                        \
    *(uint2*)&As[SLOT][(g * 32 + arow8) * 32 + acol] = pack_bf4(RV[g]);
#define G1_COMPUTE(CUR, BSLOT)                                                   \
  {                                                                              \
    short8 a[4], b[4];                                                           \
    _Pragma("unroll")                                                            \
    for (int i = 0; i < 4; ++i)                                                  \
      a[i] = *(const short8*)&As[CUR][(wm * 64 + i * 16 + l15) * 32 + quad * 8]; \
    _Pragma("unroll")                                                            \
    for (int j = 0; j < 4; ++j)                                                  \
      b[j] = *(const short8*)&Bs[BSLOT][(wn * 64 + j * 16 + l15) * 32 + quad * 8]; \
    _Pragma("unroll")                                                            \
    for (int i = 0; i < 4; ++i)                                                  \
      _Pragma("unroll")                                                          \
      for (int j = 0; j < 4; ++j)                                                \
        acc[i][j] = __builtin_amdgcn_mfma_f32_16x16x32_bf16(a[i], b[j], acc[i][j], 0, 0, 0); \
  }
#define FENCE_BAR()                                                  \
  asm volatile("s_waitcnt vmcnt(6)" ::: "memory");                   \
  asm volatile("s_waitcnt lgkmcnt(0)" ::: "memory");                 \
  __builtin_amdgcn_s_barrier();                                      \
  asm volatile("" ::: "memory");

  // prologue: issue tiles 0 and 1; stage A(0); rendezvous.
  ISSUE_A(rv0, 0);
  ISSUE_B(0, 0);
  ISSUE_A(rv1, 1);
  ISSUE_B(1, 1);
  CONVERT_A(rv0, 0);          // compiler auto-waits A(0); B(0) older than A(1) -> also done at vmcnt(6)
  FENCE_BAR();

  f32x4 acc[4][4] = {};

#define BODY(T, RV_ISS, RV_CONV)                                     \
  {                                                                  \
    const int t2 = ((T) + 2 < NT) ? (T) + 2 : NT - 1;                \
    ISSUE_A(RV_ISS, t2);                                             \
    ISSUE_B(t2, ((T) + 2) % 3);                                      \
    G1_COMPUTE((T) & 1, (T) % 3);                                    \
    CONVERT_A(RV_CONV, ((T) + 1) & 1);                               \
    FENCE_BAR();                                                     \
  }

  for (int t = 0; t < NT; t += 2) {
    BODY(t, rv0, rv1);
    BODY(t + 1, rv1, rv0);
  }
#undef BODY
#undef FENCE_BAR
#undef G1_COMPUTE
#undef CONVERT_A
#undef ISSUE_B
#undef ISSUE_A

  // epilogue: fp32 partials
  float* Pz = P + (size_t)z * (8192L * 512);
  #pragma unroll
  for (int i = 0; i < 4; ++i) {
    #pragma unroll
    for (int j = 0; j < 4; ++j) {
      const int rb = m0 + wm * 64 + i * 16 + quad * 4;
      const int cc = n0 + wn * 64 + j * 16 + l15;
      #pragma unroll
      for (int r = 0; r < 4; ++r)
        Pz[(size_t)(rb + r) * NN + cc] = acc[i][j][r];
    }
  }
}

// Xri = bf16(P[0] + P[1]) ; 4 floats per thread, vectorized
__global__ void reduce_cast(const float* __restrict__ P, u16* __restrict__ Xri) {
  const int i = blockIdx.x * 256 + threadIdx.x;     // 1M float4s
  const f4 a = ((const f4*)P)[i];
  const f4 b = ((const f4*)(P + 8192L * 512))[i];
  union { u16 h[4]; uint2 q; } pk;
  #pragma unroll
  for (int r = 0; r < 4; ++r) pk.h[r] = f2bf(a[r] + b[r]);
  ((uint2*)Xri)[i] = pk.q;
}

// ---------------------------------------------------------------------------
// Merged Q/K/V/Wot kernel: four M=8192,N=256,K=512 bf16 GEMMs as z-slices.
// ---------------------------------------------------------------------------
__global__ __launch_bounds__(256, 2)
void gemm_qkvw(const u16* __restrict__ Xri, const u16* __restrict__ Fm,
               const u16* __restrict__ qwb, const u16* __restrict__ kwb,
               const u16* __restrict__ vwb, const u16* __restrict__ owb,
               u16* __restrict__ Qb, u16* __restrict__ Kb,
               u16* __restrict__ Vt, u16* __restrict__ Wot)
{
  constexpr int N = 256, K = 512;
  __shared__ u16 As[128 * 32] __attribute__((aligned(16)));
  __shared__ u16 Bs[128 * 32] __attribute__((aligned(16)));

  const int tid  = threadIdx.x;
  const int wave = tid >> 6, lane = tid & 63;
  const int quad = lane >> 4, l15 = lane & 15;
  const int wm = wave >> 1, wn = wave & 1;
  const int m0 = blockIdx.y * 128, n0 = blockIdx.x * 128;
  const int z  = blockIdx.z;

  const u16* Ab = (z == 3) ? Fm : Xri;
  const u16* Bb = (z == 0) ? qwb : (z == 1) ? kwb : (z == 2) ? vwb : owb;
  const float alpha = (z == 3) ? (2.f / 8192.f) : 1.f;

  f32x4 acc[4][4] = {};

  const int loff0 = wave * 2048 + lane * 16;
  const int loff1 = loff0 + 1024;
  const int row0s = loff0 >> 6, kof0 = (loff0 & 63) >> 1;
  const int row1s = loff1 >> 6, kof1 = (loff1 & 63) >> 1;

  for (int k0 = 0; k0 < K; k0 += 32) {
    __syncthreads();
    gload_lds16(Ab + (size_t)(m0 + row0s) * K + k0 + kof0, (char*)As + loff0);
    gload_lds16(Ab + (size_t)(m0 + row1s) * K + k0 + kof1, (char*)As + loff1);
    gload_lds16(Bb + (size_t)(n0 + row0s) * K + k0 + kof0, (char*)Bs + loff0);
    gload_lds16(Bb + (size_t)(n0 + row1s) * K + k0 + kof1, (char*)Bs + loff1);
    __syncthreads();

    short8 a[4], b[4];
    #pragma unroll
    for (int i = 0; i < 4; ++i)
      a[i] = *(const short8*)&As[(wm * 64 + i * 16 + l15) * 32 + quad * 8];
    #pragma unroll
    for (int j = 0; j < 4; ++j)
      b[j] = *(const short8*)&Bs[(wn * 64 + j * 16 + l15) * 32 + quad * 8];
    #pragma unroll
    for (int i = 0; i < 4; ++i)
      #pragma unroll
      for (int j = 0; j < 4; ++j)
        acc[i][j] = __builtin_amdgcn_mfma_f32_16x16x32_bf16(a[i], b[j], acc[i][j], 0, 0, 0);
  }

  #pragma unroll
  for (int i = 0; i < 4; ++i) {
    #pragma unroll
    for (int j = 0; j < 4; ++j) {
      f32x4 v = acc[i][j];
      const int rb = m0 + wm * 64 + i * 16 + quad * 4;
      const int cc = n0 + wn * 64 + j * 16 + l15;
      if (z == 2) {
        const int bb = rb >> 11, ml = rb & 2047;
        union { u16 h[4]; uint2 q; } pk;
        #pragma unroll
        for (int r = 0; r < 4; ++r) pk.h[r] = f2bf(v[r]);
        *(uint2*)&Vt[((size_t)(bb << 8) + cc) * 2048 + ml] = pk.q;
      } else {
        u16* C = (z == 0) ? Qb : (z == 1) ? Kb : Wot;
        #pragma unroll
        for (int r = 0; r < 4; ++r)
          C[(size_t)(rb + r) * N + cc] = f2bf(v[r] * alpha);
      }
    }
  }
}

// ---------------------------------------------------------------------------
// General GEMM template (G4, G5, G6)
// C[m,n] = sum_k A[m,k] * B[n,k]   (B given transposed, [N][K] row-major)
// ---------------------------------------------------------------------------
template<int EPI, bool AF32>
__global__ __launch_bounds__(256, 2)
void gemm_bt(const void* __restrict__ Av, const u16* __restrict__ B,
             void* __restrict__ Cv, int M, int N, int K,
             long sA, long sB, long sC,
             const float* __restrict__ scal, float alpha)
{
  __shared__ u16 As[128 * 32] __attribute__((aligned(16)));
  __shared__ u16 Bs[128 * 32] __attribute__((aligned(16)));

  const int tid  = threadIdx.x;
  const int wave = tid >> 6, lane = tid & 63;
  const int quad = lane >> 4, l15 = lane & 15;
  const int wm = wave >> 1, wn = wave & 1;
  const int m0 = blockIdx.y * 128, n0 = blockIdx.x * 128;
  const int z  = blockIdx.z;

  const u16*   Ab = (const u16*)Av + (size_t)z * sA;
  const float* Af = (const float*)Av + (size_t)z * sA;
  const u16*   Bb = B + (size_t)z * sB;

  f32x4 acc[4][4] = {};

  const int loff0 = wave * 2048 + lane * 16;
  const int loff1 = loff0 + 1024;
  const int row0s = loff0 >> 6, kof0 = (loff0 & 63) >> 1;
  const int row1s = loff1 >> 6, kof1 = (loff1 & 63) >> 1;

  for (int k0 = 0; k0 < K; k0 += 32) {
    __syncthreads();
    if (AF32) {
      const int row = tid >> 1, half = tid & 1;
      const float* ar = Af + (size_t)(m0 + row) * K + k0 + half * 16;
      f4 p0 = *(const f4*)(ar);
      f4 p1 = *(const f4*)(ar + 4);
      f4 p2 = *(const f4*)(ar + 8);
      f4 p3 = *(const f4*)(ar + 12);
      union { u16 h[16]; uint4 q[2]; } pk;
      #pragma unroll
      for (int e = 0; e < 4; ++e) {
        pk.h[e]      = f2bf(p0[e]);
        pk.h[4 + e]  = f2bf(p1[e]);
        pk.h[8 + e]  = f2bf(p2[e]);
        pk.h[12 + e] = f2bf(p3[e]);
      }
      uint4* dst = (uint4*)&As[row * 32 + half * 16];
      dst[0] = pk.q[0]; dst[1] = pk.q[1];
    } else {
      gload_lds16(Ab + (size_t)(m0 + row0s) * K + k0 + kof0, (char*)As + loff0);
      gload_lds16(Ab + (size_t)(m0 + row1s) * K + k0 + kof1, (char*)As + loff1);
    }
    gload_lds16(Bb + (size_t)(n0 + row0s) * K + k0 + kof0, (char*)Bs + loff0);
    gload_lds16(Bb + (size_t)(n0 + row1s) * K + k0 + kof1, (char*)Bs + loff1);
    __syncthreads();

    short8 a[4], b[4];
    #pragma unroll
    for (int i = 0; i < 4; ++i)
      a[i] = *(const short8*)&As[(wm * 64 + i * 16 + l15) * 32 + quad * 8];
    #pragma unroll
    for (int j = 0; j < 4; ++j)
      b[j] = *(const short8*)&Bs[(wn * 64 + j * 16 + l15) * 32 + quad * 8];
    #pragma unroll
    for (int i = 0; i < 4; ++i)
      #pragma unroll
      for (int j = 0; j < 4; ++j)
        acc[i][j] = __builtin_amdgcn_mfma_f32_16x16x32_bf16(a[i], b[j], acc[i][j], 0, 0, 0);
  }

  float dec_l2 = 0.f, oscale = 1.f;
  if (EPI == 3) {
    float logit = *scal;
    float dec = 1.f / (1.f + expf(-logit));
    dec_l2 = log2f(dec);
  }
  if (EPI == 4) oscale = *scal;

  #pragma unroll
  for (int i = 0; i < 4; ++i) {
    #pragma unroll
    for (int j = 0; j < 4; ++j) {
      f32x4 v = acc[i][j];
      const int rb = m0 + wm * 64 + i * 16 + quad * 4;
      const int cc = n0 + wn * 64 + j * 16 + l15;
      if (EPI == 0) {
        u16* C = (u16*)Cv + (size_t)z * sC;
        #pragma unroll
        for (int r = 0; r < 4; ++r)
          C[(size_t)(rb + r) * N + cc] = f2bf(v[r] * alpha);
      } else if (EPI == 2) {
        u16* C = (u16*)Cv;
        const int bb = rb >> 11, ml = rb & 2047;
        union { u16 h[4]; uint2 q; } pk;
        #pragma unroll
        for (int r = 0; r < 4; ++r) pk.h[r] = f2bf(v[r]);
        *(uint2*)&C[((size_t)(bb << 8) + cc) * 2048 + ml] = pk.q;
      } else if (EPI == 3) {
        u16* C = (u16*)Cv + (size_t)z * sC;
        #pragma unroll
        for (int r = 0; r < 4; ++r) {
          const int d = cc - (rb + r);            // s - t
          float w = (d > 0) ? exp2f(dec_l2 * (float)(d - 1)) : 0.f;
          C[(size_t)(rb + r) * N + cc] = f2bf(v[r] * w);
        }
      } else if (EPI == 4) {
        float* C = (float*)Cv;
        #pragma unroll
        for (int r = 0; r < 4; ++r)
          C[(size_t)(rb + r) * N + cc] = v[r] * oscale;
      }
    }
  }
}

// F tables: exact integer phase reduction (n*k mod 8192) before trig.
__global__ void genF_row(u16* Fm) {           // Fm [8192][512], coalesced in j
  int idx = blockIdx.x * 256 + threadIdx.x;
  int n = idx >> 9, j = idx & 511;
  int k = (j & 255) + 1;
  int ph = (n * k) & 8191;
  float ang = (float)ph * 7.66990393942820795e-4f;  // 2*pi/8192
  float s, c; sincosf(ang, &s, &c);
  Fm[idx] = f2bf(j < 256 ? c : -s);
}
__global__ void genF_col(u16* Ft) {           // Ft [512][8192], coalesced in n
  int idx = blockIdx.x * 256 + threadIdx.x;
  int j = idx >> 13, n = idx & 8191;
  int k = (j & 255) + 1;
  int ph = (n * k) & 8191;
  float ang = (float)ph * 7.66990393942820795e-4f;
  float s, c; sincosf(ang, &s, &c);
  Ft[idx] = f2bf(j < 256 ? c : -s);
}

__global__ void cast_w4(const float* a, const float* b, const float* c, const float* d,
                        u16* oa, u16* ob, u16* oc, u16* od) {
  int i = blockIdx.x * 256 + threadIdx.x;     // 131072 each
  oa[i] = f2bf(a[i]); ob[i] = f2bf(b[i]); oc[i] = f2bf(c[i]); od[i] = f2bf(d[i]);
}

extern "C" void kernel_launch(void* const* d_in, const int* in_sizes, int n_in,
                              void* d_out, int out_size, void* d_ws, size_t ws_size,
                              hipStream_t stream)
{
  const float* x  = (const float*)d_in[0];
  const float* qw = (const float*)d_in[1];
  const float* kw = (const float*)d_in[2];
  const float* vw = (const float*)d_in[3];
  const float* ow = (const float*)d_in[4];
  const float* dl = (const float*)d_in[5];   // decay_logit
  const float* os = (const float*)d_in[6];   // out_scale
  float* out = (float*)d_out;

  char* W = (char*)d_ws;
  const size_t MB = 1024 * 1024;
  u16* Fm  = (u16*)(W);             // [8192][512]   8 MB
  u16* Ft  = (u16*)(W + 8 * MB);    // [512][8192]   8 MB
  u16* Xri = (u16*)(W + 16 * MB);   // [8192][512]   8 MB
  u16* Qb  = (u16*)(W + 24 * MB);   // [8192][256]   4 MB
  u16* Kb  = (u16*)(W + 28 * MB);   // [8192][256]   4 MB
  u16* Vt  = (u16*)(W + 32 * MB);   // [4][256][2048] 4 MB
  u16* Wot = (u16*)(W + 36 * MB);   // [8192][256]   4 MB
  u16* S   = (u16*)(W + 40 * MB);   // [4][2048][2048] 32 MB (S aliases P; P dead before G4)
  float* P = (float*)(W + 40 * MB); // [2][8192][512] fp32 32 MB split-K partials
  u16* R   = (u16*)(W + 72 * MB);   // [8192][256]   4 MB
  u16* qwb = (u16*)(W + 76 * MB);   // 4 x 256 KB
  u16* kwb = qwb + 131072;
  u16* vwb = kwb + 131072;
  u16* owb = vwb + 131072;

  genF_row<<<8192 * 512 / 256, 256, 0, stream>>>(Fm);
  genF_col<<<8192 * 512 / 256, 256, 0, stream>>>(Ft);
  cast_w4<<<131072 / 256, 256, 0, stream>>>(qw, kw, vw, ow, qwb, kwb, vwb, owb);

  // G1: Xri = x @ F           M=8192 N=512 K=8192  (A is fp32)
  // split-K=2 pipelined kernel -> fp32 partials P, then reduce+cast to bf16
  gemm_g1<<<512, 256, 0, stream>>>(x, Ft, P);
  reduce_cast<<<4096, 256, 0, stream>>>(P, Xri);

  // G2+G3 merged: q, k, v = Xri @ w^T ; Wot = (2/V) * Fm @ ow^T   (512 blocks)
  gemm_qkvw<<<dim3(2, 64, 4), 256, 0, stream>>>(Xri, Fm, qwb, kwb, vwb, owb,
                                                Qb, Kb, Vt, Wot);

  // G4: S[b] = (q k^T) .* weight   M=N=2048 K=256, z=batch
  gemm_bt<3, false><<<dim3(16, 16, 4), 256, 0, stream>>>(Qb, Kb, S, 2048, 2048, 256,
                                                         2048L * 256, 2048L * 256, 2048L * 2048, dl, 1.f);
  // G5: R[b] = S[b] @ v[b]    M=2048 N=256 K=2048
  gemm_bt<0, false><<<dim3(2, 16, 4), 256, 0, stream>>>(S, Vt, R, 2048, 256, 2048,
                                                        2048L * 2048, 256L * 2048, 2048L * 256, nullptr, 1.f);
  // G6: out = (R @ Wot^T) * out_scale   M=8192 N=8192 K=256, fp32 out
  gemm_bt<4, false><<<dim3(64, 64, 1), 256, 0, stream>>>(R, Wot, out, 8192, 8192, 256, 0, 0, 0, os, 1.f);
}

// Round 5
// 624.535 us; speedup vs baseline: 1.3889x; 1.0895x over previous
//
#include <hip/hip_runtime.h>
#include <hip/hip_bf16.h>
#include <cstdint>

// GaussMemoryStep: everything reduced to bf16 MFMA GEMMs.
// F[n,j<256]=cos(2pi(j+1)n/V), F[n,256+j]=-sin(2pi(j+1)n/V);  irfft == @ (2/V)F^T.

typedef unsigned short u16;
typedef short short8 __attribute__((ext_vector_type(8)));
typedef float f32x4 __attribute__((ext_vector_type(4)));
typedef float f4 __attribute__((ext_vector_type(4)));

__device__ __forceinline__ u16 f2bf(float f) {
  union { float f; unsigned u; } v; v.f = f;
  unsigned u = v.u;
  u += 0x7fffu + ((u >> 16) & 1u);   // round-to-nearest-even
  return (u16)(u >> 16);
}

__device__ __forceinline__ uint2 pack_bf4(f4 v) {
  union { u16 h[4]; uint2 q; } pk;
  pk.h[0] = f2bf(v[0]); pk.h[1] = f2bf(v[1]);
  pk.h[2] = f2bf(v[2]); pk.h[3] = f2bf(v[3]);
  return pk.q;
}

__device__ __forceinline__ void gload_lds16(const void* g, void* l) {
  __builtin_amdgcn_global_load_lds(
      (const __attribute__((address_space(1))) void*)g,
      (__attribute__((address_space(3))) void*)l, 16, 0, 0);
}

// ---------------------------------------------------------------------------
// G1: P[z] = x[:, z*4096:(z+1)*4096] @ Ft[:, z*4096:...]^T
// A fp32 [8192][8192], B bf16 [512][8192] ([N][K] row-major), P fp32 [2][8192][512].
// Split-K=2, XCD-chunked swizzle, counted-vmcnt pipeline, BK=64,
// XOR LDS swizzle byte^=(row&7)<<4 on As (write+read) and Bs (pre-swizzled
// global source + swizzled read; both-sides rule).
// vmcnt ledger (per wave, per iter), ORDER PINNED by sched_barrier(0):
//   entering iter t: A(t+1)x8 outstanding.
//   ISSUE_B(t+1)x4 -> 12;  ISSUE_A(t+2)x8 -> 20.
//   CONVERT_A(t+1) implicit wait vmcnt(12): drains A(t+1)x8 -> 12.
//   FENCE vmcnt(8): drains B(t+1)x4 (needed next iter), keeps A(t+2)x8 in flight.
// ---------------------------------------------------------------------------
__global__ __launch_bounds__(256, 2)
void gemm_g1(const float* __restrict__ A, const u16* __restrict__ B,
             float* __restrict__ P)
{
  constexpr int NN = 512, KK = 8192, KC = 4096;
  constexpr int NT = KC / 64;   // 64 K-iterations per block, BK=64

  __shared__ u16 As[2][128 * 64] __attribute__((aligned(16)));
  __shared__ u16 Bs[2][128 * 64] __attribute__((aligned(16)));

  const int tid  = threadIdx.x;
  const int wave = tid >> 6, lane = tid & 63;
  const int quad = lane >> 4, l15 = lane & 15;
  const int wm = wave >> 1, wn = wave & 1;
  const int swz8 = (l15 & 7) << 3;   // read-side XOR, u16 units

  // XCD-chunked bijective swizzle: xcd = lid%8 owns natural ids [xcd*64, xcd*64+64)
  const int lid = blockIdx.x;                 // 0..511
  const int nat = (lid & 7) * 64 + (lid >> 3);
  const int y = nat >> 3, rem = nat & 7;
  const int x = rem & 3, z = rem >> 2;        // y: M-panel, x: N-panel, z: K-chunk
  const int m0 = y * 128, n0 = x * 128, k00 = z * KC;

  // B staging: tile 128 rows x 64 u16 (128B/row). 4 gload calls, call h covers
  // rows [h*32, h*32+32). LDS dest linear; global source pre-XOR-swizzled.
  const int brow = tid >> 3;                                    // 0..31
  const int bswz = ((tid & 7) * 8) ^ (((tid >> 3) & 7) << 3);   // u16
  const u16* Bp = B + (size_t)(n0 + brow) * KK + k00 + bswz;
  const int bloff = tid * 16;                                   // byte, + h*4096

  // A staging: tile 128 rows x 64 fp32. 8 reg-loads, load g covers rows
  // [g*16, g*16+16); thread t -> row g*16+(t>>4), 16B at float-col (t&15)*4.
  const int arow16 = tid >> 4;
  const int acolf  = (tid & 15) * 4;
  const float* Ap = A + (size_t)(m0 + arow16) * KK + k00 + acolf;
  const int awz = ((tid & 15) * 4) ^ (((tid >> 4) & 7) << 3);   // swizzled u16 col

  f4 rv0[8], rv1[8];                   // two A-prefetch stages (static roles)

#define ISSUE_A(RV, T)                                               \
  _Pragma("unroll")                                                  \
  for (int g = 0; g < 8; ++g)                                        \
    RV[g] = *(const f4*)(Ap + (size_t)g * 16 * KK + (size_t)(T) * 64);
#define ISSUE_B(T, SLOT)                                             \
  _Pragma("unroll")                                                  \
  for (int h = 0; h < 4; ++h)                                        \
    gload_lds16(Bp + (size_t)h * 32 * KK + (size_t)(T) * 64,         \
                (char*)Bs[SLOT] + h * 4096 + bloff);
#define CONVERT_A(RV, SLOT)                                          \
  _Pragma("unroll")                                                  \
  for (int g = 0; g < 8; ++g)                                        \
    *(uint2*)&As[SLOT][(g * 16 + arow16) * 64 + awz] = pack_bf4(RV[g]);
#define G1_COMPUTE(CUR)                                                          \
  _Pragma("unroll")                                                              \
  for (int ks = 0; ks < 2; ++ks) {                                               \
    short8 a[4], b[4];                                                           \
    _Pragma("unroll")                                                            \
    for (int i = 0; i < 4; ++i)                                                  \
      a[i] = *(const short8*)&As[CUR][(wm * 64 + i * 16 + l15) * 64 +            \
                                      ((ks * 32 + quad * 8) ^ swz8)];            \
    _Pragma("unroll")                                                            \
    for (int j = 0; j < 4; ++j)                                                  \
      b[j] = *(const short8*)&Bs[CUR][(wn * 64 + j * 16 + l15) * 64 +            \
                                      ((ks * 32 + quad * 8) ^ swz8)];            \
    _Pragma("unroll")                                                            \
    for (int i = 0; i < 4; ++i)                                                  \
      _Pragma("unroll")                                                          \
      for (int j = 0; j < 4; ++j)                                                \
        acc[i][j] = __builtin_amdgcn_mfma_f32_16x16x32_bf16(a[i], b[j], acc[i][j], 0, 0, 0); \
  }
#define SB() __builtin_amdgcn_sched_barrier(0)
#define FENCE_BAR()                                                  \
  asm volatile("s_waitcnt vmcnt(8)" ::: "memory");                   \
  asm volatile("s_waitcnt lgkmcnt(0)" ::: "memory");                 \
  __builtin_amdgcn_s_barrier();                                      \
  asm volatile("" ::: "memory");

  // prologue: A(0)x8, B(0)x4, A(1)x8 (order pinned) -> 20 outstanding.
  // CONVERT_A(rv0) implicit-waits A(0) -> 12; FENCE vmcnt(8) drains B(0),
  // keeps A(1)x8 in flight (the loop-entry invariant).
  ISSUE_A(rv0, 0);
  ISSUE_B(0, 0);
  SB();
  ISSUE_A(rv1, 1);
  SB();
  CONVERT_A(rv0, 0);
  FENCE_BAR();

  f32x4 acc[4][4] = {};

#define BODY(T, RV_ISS, RV_CONV)                                     \
  {                                                                  \
    const int t2 = ((T) + 2 < NT) ? (T) + 2 : NT - 1;                \
    ISSUE_B((T) + 1 < NT ? (T) + 1 : NT - 1, ((T) + 1) & 1);         \
    SB();                                                            \
    ISSUE_A(RV_ISS, t2);                                             \
    SB();                                                            \
    G1_COMPUTE((T) & 1);                                             \
    CONVERT_A(RV_CONV, ((T) + 1) & 1);                               \
    FENCE_BAR();                                                     \
  }

  for (int t = 0; t < NT; t += 2) {
    BODY(t, rv0, rv1);
    BODY(t + 1, rv1, rv0);
  }
#undef BODY
#undef FENCE_BAR
#undef SB
#undef G1_COMPUTE
#undef CONVERT_A
#undef ISSUE_B
#undef ISSUE_A

  // epilogue: fp32 partials
  float* Pz = P + (size_t)z * (8192L * 512);
  #pragma unroll
  for (int i = 0; i < 4; ++i) {
    #pragma unroll
    for (int j = 0; j < 4; ++j) {
      const int rb = m0 + wm * 64 + i * 16 + quad * 4;
      const int cc = n0 + wn * 64 + j * 16 + l15;
      #pragma unroll
      for (int r = 0; r < 4; ++r)
        Pz[(size_t)(rb + r) * NN + cc] = acc[i][j][r];
    }
  }
}

// O = bf16(P[i] + P[i + half_f4]) ; 4 floats per thread, exact grid
__global__ void reduce_cast(const float* __restrict__ P, u16* __restrict__ O,
                            int half_f4) {
  const int i = blockIdx.x * 256 + threadIdx.x;
  const f4 a = ((const f4*)P)[i];
  const f4 b = ((const f4*)P)[i + half_f4];
  union { u16 h[4]; uint2 q; } pk;
  #pragma unroll
  for (int r = 0; r < 4; ++r) pk.h[r] = f2bf(a[r] + b[r]);
  ((uint2*)O)[i] = pk.q;
}

// ---------------------------------------------------------------------------
// Merged Q/K/V/Wot kernel: four M=8192,N=256,K=512 bf16 GEMMs as z-slices.
// ---------------------------------------------------------------------------
__global__ __launch_bounds__(256, 2)
void gemm_qkvw(const u16* __restrict__ Xri, const u16* __restrict__ Fm,
               const u16* __restrict__ qwb, const u16* __restrict__ kwb,
               const u16* __restrict__ vwb, const u16* __restrict__ owb,
               u16* __restrict__ Qb, u16* __restrict__ Kb,
               u16* __restrict__ Vt, u16* __restrict__ Wot)
{
  constexpr int N = 256, K = 512;
  __shared__ u16 As[128 * 32] __attribute__((aligned(16)));
  __shared__ u16 Bs[128 * 32] __attribute__((aligned(16)));

  const int tid  = threadIdx.x;
  const int wave = tid >> 6, lane = tid & 63;
  const int quad = lane >> 4, l15 = lane & 15;
  const int wm = wave >> 1, wn = wave & 1;
  const int m0 = blockIdx.y * 128, n0 = blockIdx.x * 128;
  const int z  = blockIdx.z;

  const u16* Ab = (z == 3) ? Fm : Xri;
  const u16* Bb = (z == 0) ? qwb : (z == 1) ? kwb : (z == 2) ? vwb : owb;
  const float alpha = (z == 3) ? (2.f / 8192.f) : 1.f;

  f32x4 acc[4][4] = {};

  const int loff0 = wave * 2048 + lane * 16;
  const int loff1 = loff0 + 1024;
  const int row0s = loff0 >> 6, kof0 = (loff0 & 63) >> 1;
  const int row1s = loff1 >> 6, kof1 = (loff1 & 63) >> 1;

  for (int k0 = 0; k0 < K; k0 += 32) {
    __syncthreads();
    gload_lds16(Ab + (size_t)(m0 + row0s) * K + k0 + kof0, (char*)As + loff0);
    gload_lds16(Ab + (size_t)(m0 + row1s) * K + k0 + kof1, (char*)As + loff1);
    gload_lds16(Bb + (size_t)(n0 + row0s) * K + k0 + kof0, (char*)Bs + loff0);
    gload_lds16(Bb + (size_t)(n0 + row1s) * K + k0 + kof1, (char*)Bs + loff1);
    __syncthreads();

    short8 a[4], b[4];
    #pragma unroll
    for (int i = 0; i < 4; ++i)
      a[i] = *(const short8*)&As[(wm * 64 + i * 16 + l15) * 32 + quad * 8];
    #pragma unroll
    for (int j = 0; j < 4; ++j)
      b[j] = *(const short8*)&Bs[(wn * 64 + j * 16 + l15) * 32 + quad * 8];
    #pragma unroll
    for (int i = 0; i < 4; ++i)
      #pragma unroll
      for (int j = 0; j < 4; ++j)
        acc[i][j] = __builtin_amdgcn_mfma_f32_16x16x32_bf16(a[i], b[j], acc[i][j], 0, 0, 0);
  }

  #pragma unroll
  for (int i = 0; i < 4; ++i) {
    #pragma unroll
    for (int j = 0; j < 4; ++j) {
      f32x4 v = acc[i][j];
      const int rb = m0 + wm * 64 + i * 16 + quad * 4;
      const int cc = n0 + wn * 64 + j * 16 + l15;
      if (z == 2) {
        const int bb = rb >> 11, ml = rb & 2047;
        union { u16 h[4]; uint2 q; } pk;
        #pragma unroll
        for (int r = 0; r < 4; ++r) pk.h[r] = f2bf(v[r]);
        *(uint2*)&Vt[((size_t)(bb << 8) + cc) * 2048 + ml] = pk.q;
      } else {
        u16* C = (z == 0) ? Qb : (z == 1) ? Kb : Wot;
        #pragma unroll
        for (int r = 0; r < 4; ++r)
          C[(size_t)(rb + r) * N + cc] = f2bf(v[r] * alpha);
      }
    }
  }
}

// ---------------------------------------------------------------------------
// G5: R partials = S[b][:, k] @ Vt[b]  with trapezoidal K (S strictly upper
// block-triangular) and split-K=2.  P5 fp32 [2][8192][256].
// ---------------------------------------------------------------------------
__global__ __launch_bounds__(256, 2)
void gemm_g5(const u16* __restrict__ S, const u16* __restrict__ Vt,
             float* __restrict__ P5)
{
  constexpr int N = 256, K = 2048;
  __shared__ u16 As[128 * 32] __attribute__((aligned(16)));
  __shared__ u16 Bs[128 * 32] __attribute__((aligned(16)));

  const int tid  = threadIdx.x;
  const int wave = tid >> 6, lane = tid & 63;
  const int quad = lane >> 4, l15 = lane & 15;
  const int wm = wave >> 1, wn = wave & 1;
  const int m0 = blockIdx.y * 128, n0 = blockIdx.x * 128;
  const int batch = blockIdx.z & 3, half = blockIdx.z >> 2;

  const u16* Ab = S  + (size_t)batch * 2048 * 2048;
  const u16* Bb = Vt + (size_t)batch * 256 * 2048;

  int kbeg = half * 1024;
  if (m0 > kbeg) kbeg = m0;          // S[t,s]==0 for s<=t -> skip left of diag
  const int kend = half * 1024 + 1024;

  f32x4 acc[4][4] = {};

  const int loff0 = wave * 2048 + lane * 16;
  const int loff1 = loff0 + 1024;
  const int row0s = loff0 >> 6, kof0 = (loff0 & 63) >> 1;
  const int row1s = loff1 >> 6, kof1 = (loff1 & 63) >> 1;

  for (int k0 = kbeg; k0 < kend; k0 += 32) {
    __syncthreads();
    gload_lds16(Ab + (size_t)(m0 + row0s) * K + k0 + kof0, (char*)As + loff0);
    gload_lds16(Ab + (size_t)(m0 + row1s) * K + k0 + kof1, (char*)As + loff1);
    gload_lds16(Bb + (size_t)(n0 + row0s) * K + k0 + kof0, (char*)Bs + loff0);
    gload_lds16(Bb + (size_t)(n0 + row1s) * K + k0 + kof1, (char*)Bs + loff1);
    __syncthreads();

    short8 a[4], b[4];
    #pragma unroll
    for (int i = 0; i < 4; ++i)
      a[i] = *(const short8*)&As[(wm * 64 + i * 16 + l15) * 32 + quad * 8];
    #pragma unroll
    for (int j = 0; j < 4; ++j)
      b[j] = *(const short8*)&Bs[(wn * 64 + j * 16 + l15) * 32 + quad * 8];
    #pragma unroll
    for (int i = 0; i < 4; ++i)
      #pragma unroll
      for (int j = 0; j < 4; ++j)
        acc[i][j] = __builtin_amdgcn_mfma_f32_16x16x32_bf16(a[i], b[j], acc[i][j], 0, 0, 0);
  }

  float* Pz = P5 + (size_t)half * (8192L * 256) + (size_t)batch * 2048 * 256;
  #pragma unroll
  for (int i = 0; i < 4; ++i) {
    #pragma unroll
    for (int j = 0; j < 4; ++j) {
      const int rb = m0 + wm * 64 + i * 16 + quad * 4;
      const int cc = n0 + wn * 64 + j * 16 + l15;
      #pragma unroll
      for (int r = 0; r < 4; ++r)
        Pz[(size_t)(rb + r) * N + cc] = acc[i][j][r];
    }
  }
}

// ---------------------------------------------------------------------------
// General GEMM template (G4, G6)
// C[m,n] = sum_k A[m,k] * B[n,k]   (B given transposed, [N][K] row-major)
// TRI: skip blocks strictly below the diagonal (output block-triangular).
// ---------------------------------------------------------------------------
template<int EPI, bool AF32, bool TRI>
__global__ __launch_bounds__(256, 2)
void gemm_bt(const void* __restrict__ Av, const u16* __restrict__ B,
             void* __restrict__ Cv, int M, int N, int K,
             long sA, long sB, long sC,
             const float* __restrict__ scal, float alpha)
{
  if (TRI && blockIdx.x < blockIdx.y) return;

  __shared__ u16 As[128 * 32] __attribute__((aligned(16)));
  __shared__ u16 Bs[128 * 32] __attribute__((aligned(16)));

  const int tid  = threadIdx.x;
  const int wave = tid >> 6, lane = tid & 63;
  const int quad = lane >> 4, l15 = lane & 15;
  const int wm = wave >> 1, wn = wave & 1;
  const int m0 = blockIdx.y * 128, n0 = blockIdx.x * 128;
  const int z  = blockIdx.z;

  const u16*   Ab = (const u16*)Av + (size_t)z * sA;
  const float* Af = (const float*)Av + (size_t)z * sA;
  const u16*   Bb = B + (size_t)z * sB;

  f32x4 acc[4][4] = {};

  const int loff0 = wave * 2048 + lane * 16;
  const int loff1 = loff0 + 1024;
  const int row0s = loff0 >> 6, kof0 = (loff0 & 63) >> 1;
  const int row1s = loff1 >> 6, kof1 = (loff1 & 63) >> 1;

  for (int k0 = 0; k0 < K; k0 += 32) {
    __syncthreads();
    if (AF32) {
      const int row = tid >> 1, half = tid & 1;
      const float* ar = Af + (size_t)(m0 + row) * K + k0 + half * 16;
      f4 p0 = *(const f4*)(ar);
      f4 p1 = *(const f4*)(ar + 4);
      f4 p2 = *(const f4*)(ar + 8);
      f4 p3 = *(const f4*)(ar + 12);
      union { u16 h[16]; uint4 q[2]; } pk;
      #pragma unroll
      for (int e = 0; e < 4; ++e) {
        pk.h[e]      = f2bf(p0[e]);
        pk.h[4 + e]  = f2bf(p1[e]);
        pk.h[8 + e]  = f2bf(p2[e]);
        pk.h[12 + e] = f2bf(p3[e]);
      }
      uint4* dst = (uint4*)&As[row * 32 + half * 16];
      dst[0] = pk.q[0]; dst[1] = pk.q[1];
    } else {
      gload_lds16(Ab + (size_t)(m0 + row0s) * K + k0 + kof0, (char*)As + loff0);
      gload_lds16(Ab + (size_t)(m0 + row1s) * K + k0 + kof1, (char*)As + loff1);
    }
    gload_lds16(Bb + (size_t)(n0 + row0s) * K + k0 + kof0, (char*)Bs + loff0);
    gload_lds16(Bb + (size_t)(n0 + row1s) * K + k0 + kof1, (char*)Bs + loff1);
    __syncthreads();

    short8 a[4], b[4];
    #pragma unroll
    for (int i = 0; i < 4; ++i)
      a[i] = *(const short8*)&As[(wm * 64 + i * 16 + l15) * 32 + quad * 8];
    #pragma unroll
    for (int j = 0; j < 4; ++j)
      b[j] = *(const short8*)&Bs[(wn * 64 + j * 16 + l15) * 32 + quad * 8];
    #pragma unroll
    for (int i = 0; i < 4; ++i)
      #pragma unroll
      for (int j = 0; j < 4; ++j)
        acc[i][j] = __builtin_amdgcn_mfma_f32_16x16x32_bf16(a[i], b[j], acc[i][j], 0, 0, 0);
  }

  float dec_l2 = 0.f, oscale = 1.f;
  if (EPI == 3) {
    float logit = *scal;
    float dec = 1.f / (1.f + expf(-logit));
    dec_l2 = log2f(dec);
  }
  if (EPI == 4) oscale = *scal;

  #pragma unroll
  for (int i = 0; i < 4; ++i) {
    #pragma unroll
    for (int j = 0; j < 4; ++j) {
      f32x4 v = acc[i][j];
      const int rb = m0 + wm * 64 + i * 16 + quad * 4;
      const int cc = n0 + wn * 64 + j * 16 + l15;
      if (EPI == 0) {
        u16* C = (u16*)Cv + (size_t)z * sC;
        #pragma unroll
        for (int r = 0; r < 4; ++r)
          C[(size_t)(rb + r) * N + cc] = f2bf(v[r] * alpha);
      } else if (EPI == 3) {
        u16* C = (u16*)Cv + (size_t)z * sC;
        #pragma unroll
        for (int r = 0; r < 4; ++r) {
          const int d = cc - (rb + r);            // s - t
          float w = (d > 0) ? exp2f(dec_l2 * (float)(d - 1)) : 0.f;
          C[(size_t)(rb + r) * N + cc] = f2bf(v[r] * w);
        }
      } else if (EPI == 4) {
        float* C = (float*)Cv;
        #pragma unroll
        for (int r = 0; r < 4; ++r)
          C[(size_t)(rb + r) * N + cc] = v[r] * oscale;
      }
    }
  }
}

// F tables: exact integer phase reduction (n*k mod 8192) before trig.
__global__ void genF_row(u16* Fm) {           // Fm [8192][512], coalesced in j
  int idx = blockIdx.x * 256 + threadIdx.x;
  int n = idx >> 9, j = idx & 511;
  int k = (j & 255) + 1;
  int ph = (n * k) & 8191;
  float ang = (float)ph * 7.66990393942820795e-4f;  // 2*pi/8192
  float s, c; sincosf(ang, &s, &c);
  Fm[idx] = f2bf(j < 256 ? c : -s);
}
__global__ void genF_col(u16* Ft) {           // Ft [512][8192], coalesced in n
  int idx = blockIdx.x * 256 + threadIdx.x;
  int j = idx >> 13, n = idx & 8191;
  int k = (j & 255) + 1;
  int ph = (n * k) & 8191;
  float ang = (float)ph * 7.66990393942820795e-4f;
  float s, c; sincosf(ang, &s, &c);
  Ft[idx] = f2bf(j < 256 ? c : -s);
}

__global__ void cast_w4(const float* a, const float* b, const float* c, const float* d,
                        u16* oa, u16* ob, u16* oc, u16* od) {
  int i = blockIdx.x * 256 + threadIdx.x;     // 131072 each
  oa[i] = f2bf(a[i]); ob[i] = f2bf(b[i]); oc[i] = f2bf(c[i]); od[i] = f2bf(d[i]);
}

extern "C" void kernel_launch(void* const* d_in, const int* in_sizes, int n_in,
                              void* d_out, int out_size, void* d_ws, size_t ws_size,
                              hipStream_t stream)
{
  const float* x  = (const float*)d_in[0];
  const float* qw = (const float*)d_in[1];
  const float* kw = (const float*)d_in[2];
  const float* vw = (const float*)d_in[3];
  const float* ow = (const float*)d_in[4];
  const float* dl = (const float*)d_in[5];   // decay_logit
  const float* os = (const float*)d_in[6];   // out_scale
  float* out = (float*)d_out;

  char* W = (char*)d_ws;
  const size_t MB = 1024 * 1024;
  u16* Fm  = (u16*)(W);             // [8192][512]   8 MB   (dead after qkvw)
  u16* Ft  = (u16*)(W + 8 * MB);    // [512][8192]   8 MB   (dead after G1)
  u16* Xri = (u16*)(W + 16 * MB);   // [8192][512]   8 MB
  u16* Qb  = (u16*)(W + 24 * MB);   // [8192][256]   4 MB
  u16* Kb  = (u16*)(W + 28 * MB);   // [8192][256]   4 MB
  u16* Vt  = (u16*)(W + 32 * MB);   // [4][256][2048] 4 MB
  u16* Wot = (u16*)(W + 36 * MB);   // [8192][256]   4 MB
  u16* S   = (u16*)(W + 40 * MB);   // [4][2048][2048] 32 MB (aliases P; P dead before G4)
  float* P = (float*)(W + 40 * MB); // [2][8192][512] fp32 32 MB G1 split-K partials
  float* P5 = (float*)(W);          // [2][8192][256] fp32 16 MB G5 partials (over Fm/Ft, dead)
  u16* R   = (u16*)(W + 72 * MB);   // [8192][256]   4 MB
  u16* qwb = (u16*)(W + 76 * MB);   // 4 x 256 KB
  u16* kwb = qwb + 131072;
  u16* vwb = kwb + 131072;
  u16* owb = vwb + 131072;

  genF_row<<<8192 * 512 / 256, 256, 0, stream>>>(Fm);
  genF_col<<<8192 * 512 / 256, 256, 0, stream>>>(Ft);
  cast_w4<<<131072 / 256, 256, 0, stream>>>(qw, kw, vw, ow, qwb, kwb, vwb, owb);

  // G1: Xri = x @ F   M=8192 N=512 K=8192 (A fp32) -> fp32 partials, reduce
  gemm_g1<<<512, 256, 0, stream>>>(x, Ft, P);
  reduce_cast<<<4096, 256, 0, stream>>>(P, Xri, 8192 * 512 / 4);

  // G2+G3 merged: q, k, v = Xri @ w^T ; Wot = (2/V) * Fm @ ow^T   (512 blocks)
  gemm_qkvw<<<dim3(2, 64, 4), 256, 0, stream>>>(Xri, Fm, qwb, kwb, vwb, owb,
                                                Qb, Kb, Vt, Wot);

  // G4: S[b] = (q k^T) .* weight   M=N=2048 K=256, z=batch.  Upper-tri blocks only.
  gemm_bt<3, false, true><<<dim3(16, 16, 4), 256, 0, stream>>>(Qb, Kb, S, 2048, 2048, 256,
                                                               2048L * 256, 2048L * 256, 2048L * 2048, dl, 1.f);
  // G5: R[b] = S[b] @ v[b]   trapezoidal K + split-K=2 -> fp32 partials, reduce
  gemm_g5<<<dim3(2, 16, 8), 256, 0, stream>>>(S, Vt, P5);
  reduce_cast<<<2048, 256, 0, stream>>>(P5, R, 8192 * 256 / 4);

  // G6: out = (R @ Wot^T) * out_scale   M=8192 N=8192 K=256, fp32 out
  gemm_bt<4, false, false><<<dim3(64, 64, 1), 256, 0, stream>>>(R, Wot, out, 8192, 8192, 256, 0, 0, 0, os, 1.f);
}

// Round 6
// 622.579 us; speedup vs baseline: 1.3932x; 1.0031x over previous
//
#include <hip/hip_runtime.h>
#include <hip/hip_bf16.h>
#include <cstdint>

// GaussMemoryStep: everything reduced to bf16 MFMA GEMMs.
// F[n,j<256]=cos(2pi(j+1)n/V), F[n,256+j]=-sin(2pi(j+1)n/V);  irfft == @ (2/V)F^T.

typedef unsigned short u16;
typedef short short8 __attribute__((ext_vector_type(8)));
typedef float f32x4 __attribute__((ext_vector_type(4)));
typedef float f4 __attribute__((ext_vector_type(4)));

__device__ __forceinline__ u16 f2bf(float f) {
  union { float f; unsigned u; } v; v.f = f;
  unsigned u = v.u;
  u += 0x7fffu + ((u >> 16) & 1u);   // round-to-nearest-even
  return (u16)(u >> 16);
}

__device__ __forceinline__ uint2 pack_bf4(f4 v) {
  union { u16 h[4]; uint2 q; } pk;
  pk.h[0] = f2bf(v[0]); pk.h[1] = f2bf(v[1]);
  pk.h[2] = f2bf(v[2]); pk.h[3] = f2bf(v[3]);
  return pk.q;
}

__device__ __forceinline__ void gload_lds16(const void* g, void* l) {
  __builtin_amdgcn_global_load_lds(
      (const __attribute__((address_space(1))) void*)g,
      (__attribute__((address_space(3))) void*)l, 16, 0, 0);
}

// ---------------------------------------------------------------------------
// G1: P[z] = x[:, z*4096:(z+1)*4096] @ Ft[:, z*4096:...]^T   (unchanged, r5)
// ---------------------------------------------------------------------------
__global__ __launch_bounds__(256, 2)
void gemm_g1(const float* __restrict__ A, const u16* __restrict__ B,
             float* __restrict__ P)
{
  constexpr int NN = 512, KK = 8192, KC = 4096;
  constexpr int NT = KC / 64;   // 64 K-iterations per block, BK=64

  __shared__ u16 As[2][128 * 64] __attribute__((aligned(16)));
  __shared__ u16 Bs[2][128 * 64] __attribute__((aligned(16)));

  const int tid  = threadIdx.x;
  const int wave = tid >> 6, lane = tid & 63;
  const int quad = lane >> 4, l15 = lane & 15;
  const int wm = wave >> 1, wn = wave & 1;
  const int swz8 = (l15 & 7) << 3;   // read-side XOR, u16 units

  const int lid = blockIdx.x;                 // 0..511
  const int nat = (lid & 7) * 64 + (lid >> 3);
  const int y = nat >> 3, rem = nat & 7;
  const int x = rem & 3, z = rem >> 2;        // y: M-panel, x: N-panel, z: K-chunk
  const int m0 = y * 128, n0 = x * 128, k00 = z * KC;

  const int brow = tid >> 3;                                    // 0..31
  const int bswz = ((tid & 7) * 8) ^ (((tid >> 3) & 7) << 3);   // u16
  const u16* Bp = B + (size_t)(n0 + brow) * KK + k00 + bswz;
  const int bloff = tid * 16;                                   // byte, + h*4096

  const int arow16 = tid >> 4;
  const int acolf  = (tid & 15) * 4;
  const float* Ap = A + (size_t)(m0 + arow16) * KK + k00 + acolf;
  const int awz = ((tid & 15) * 4) ^ (((tid >> 4) & 7) << 3);   // swizzled u16 col

  f4 rv0[8], rv1[8];

#define ISSUE_A(RV, T)                                               \
  _Pragma("unroll")                                                  \
  for (int g = 0; g < 8; ++g)                                        \
    RV[g] = *(const f4*)(Ap + (size_t)g * 16 * KK + (size_t)(T) * 64);
#define ISSUE_B(T, SLOT)                                             \
  _Pragma("unroll")                                                  \
  for (int h = 0; h < 4; ++h)                                        \
    gload_lds16(Bp + (size_t)h * 32 * KK + (size_t)(T) * 64,         \
                (char*)Bs[SLOT] + h * 4096 + bloff);
#define CONVERT_A(RV, SLOT)                                          \
  _Pragma("unroll")                                                  \
  for (int g = 0; g < 8; ++g)                                        \
    *(uint2*)&As[SLOT][(g * 16 + arow16) * 64 + awz] = pack_bf4(RV[g]);
#define G1_COMPUTE(CUR)                                                          \
  _Pragma("unroll")                                                              \
  for (int ks = 0; ks < 2; ++ks) {                                               \
    short8 a[4], b[4];                                                           \
    _Pragma("unroll")                                                            \
    for (int i = 0; i < 4; ++i)                                                  \
      a[i] = *(const short8*)&As[CUR][(wm * 64 + i * 16 + l15) * 64 +            \
                                      ((ks * 32 + quad * 8) ^ swz8)];            \
    _Pragma("unroll")                                                            \
    for (int j = 0; j < 4; ++j)                                                  \
      b[j] = *(const short8*)&Bs[CUR][(wn * 64 + j * 16 + l15) * 64 +            \
                                      ((ks * 32 + quad * 8) ^ swz8)];            \
    _Pragma("unroll")                                                            \
    for (int i = 0; i < 4; ++i)                                                  \
      _Pragma("unroll")                                                          \
      for (int j = 0; j < 4; ++j)                                                \
        acc[i][j] = __builtin_amdgcn_mfma_f32_16x16x32_bf16(a[i], b[j], acc[i][j], 0, 0, 0); \
  }
#define SB() __builtin_amdgcn_sched_barrier(0)
#define FENCE_BAR()                                                  \
  asm volatile("s_waitcnt vmcnt(8)" ::: "memory");                   \
  asm volatile("s_waitcnt lgkmcnt(0)" ::: "memory");                 \
  __builtin_amdgcn_s_barrier();                                      \
  asm volatile("" ::: "memory");

  ISSUE_A(rv0, 0);
  ISSUE_B(0, 0);
  SB();
  ISSUE_A(rv1, 1);
  SB();
  CONVERT_A(rv0, 0);
  FENCE_BAR();

  f32x4 acc[4][4] = {};

#define BODY(T, RV_ISS, RV_CONV)                                     \
  {                                                                  \
    const int t2 = ((T) + 2 < NT) ? (T) + 2 : NT - 1;                \
    ISSUE_B((T) + 1 < NT ? (T) + 1 : NT - 1, ((T) + 1) & 1);         \
    SB();                                                            \
    ISSUE_A(RV_ISS, t2);                                             \
    SB();                                                            \
    G1_COMPUTE((T) & 1);                                             \
    CONVERT_A(RV_CONV, ((T) + 1) & 1);                               \
    FENCE_BAR();                                                     \
  }

  for (int t = 0; t < NT; t += 2) {
    BODY(t, rv0, rv1);
    BODY(t + 1, rv1, rv0);
  }
#undef BODY
#undef FENCE_BAR
#undef SB
#undef G1_COMPUTE
#undef CONVERT_A
#undef ISSUE_B
#undef ISSUE_A

  float* Pz = P + (size_t)z * (8192L * 512);
  #pragma unroll
  for (int i = 0; i < 4; ++i) {
    #pragma unroll
    for (int j = 0; j < 4; ++j) {
      const int rb = m0 + wm * 64 + i * 16 + quad * 4;
      const int cc = n0 + wn * 64 + j * 16 + l15;
      #pragma unroll
      for (int r = 0; r < 4; ++r)
        Pz[(size_t)(rb + r) * NN + cc] = acc[i][j][r];
    }
  }
}

// O = bf16(P[i] + P[i + half_f4])
__global__ void reduce_cast(const float* __restrict__ P, u16* __restrict__ O,
                            int half_f4) {
  const int i = blockIdx.x * 256 + threadIdx.x;
  const f4 a = ((const f4*)P)[i];
  const f4 b = ((const f4*)P)[i + half_f4];
  union { u16 h[4]; uint2 q; } pk;
  #pragma unroll
  for (int r = 0; r < 4; ++r) pk.h[r] = f2bf(a[r] + b[r]);
  ((uint2*)O)[i] = pk.q;
}

// ---------------------------------------------------------------------------
// Shared pipelined bf16 K-loop (T3 2-phase minimum): BK=64, 2 LDS buffers,
// {stage(t+1) -> compute(t) -> vmcnt(0) -> barrier} -- ONE barrier per iter,
// load latency hidden under compute (operands here are L2-resident).
// LDS XOR swizzle: global source pre-swizzled, read XOR (row&7)<<3 (u16).
// A,B both bf16 [rows][K] row-major; tile 128x128, 4 waves, acc 4x4.
// ---------------------------------------------------------------------------
__device__ __forceinline__ void kloop_p(
    const u16* __restrict__ Ab, const u16* __restrict__ Bb, int K,
    int m0, int n0, int kbeg, int kend, int tid,
    u16* As, u16* Bs, f32x4 (&acc)[4][4])
{
  const int wave = tid >> 6, lane = tid & 63;
  const int quad = lane >> 4, l15 = lane & 15;
  const int wm = wave >> 1, wn = wave & 1;
  const int swz8 = (l15 & 7) << 3;

  const int brow = tid >> 3;                                    // 0..31
  const int rswz = ((tid & 7) * 8) ^ ((brow & 7) << 3);         // u16
  const u16* Apg = Ab + (size_t)(m0 + brow) * K + rswz;
  const u16* Bpg = Bb + (size_t)(n0 + brow) * K + rswz;
  const int dof = tid * 16;                                     // byte

#define STG_P(K0, SLOT)                                                     \
  _Pragma("unroll")                                                         \
  for (int h = 0; h < 4; ++h) {                                             \
    gload_lds16(Apg + (size_t)h * 32 * K + (K0),                            \
                (char*)As + (SLOT) * 16384 + h * 4096 + dof);               \
    gload_lds16(Bpg + (size_t)h * 32 * K + (K0),                            \
                (char*)Bs + (SLOT) * 16384 + h * 4096 + dof);               \
  }

  STG_P(kbeg, 0);
  asm volatile("s_waitcnt vmcnt(0)" ::: "memory");
  __builtin_amdgcn_s_barrier();
  asm volatile("" ::: "memory");

  int buf = 0;
  for (int k0 = kbeg; k0 < kend; k0 += 64) {
    if (k0 + 64 < kend) STG_P(k0 + 64, buf ^ 1);
    #pragma unroll
    for (int ks = 0; ks < 2; ++ks) {
      short8 a[4], b[4];
      #pragma unroll
      for (int i = 0; i < 4; ++i)
        a[i] = *(const short8*)&As[buf * 8192 + (wm * 64 + i * 16 + l15) * 64 +
                                   ((ks * 32 + quad * 8) ^ swz8)];
      #pragma unroll
      for (int j = 0; j < 4; ++j)
        b[j] = *(const short8*)&Bs[buf * 8192 + (wn * 64 + j * 16 + l15) * 64 +
                                   ((ks * 32 + quad * 8) ^ swz8)];
      #pragma unroll
      for (int i = 0; i < 4; ++i)
        #pragma unroll
        for (int j = 0; j < 4; ++j)
          acc[i][j] = __builtin_amdgcn_mfma_f32_16x16x32_bf16(a[i], b[j], acc[i][j], 0, 0, 0);
    }
    asm volatile("s_waitcnt vmcnt(0)" ::: "memory");
    __builtin_amdgcn_s_barrier();
    asm volatile("" ::: "memory");
    buf ^= 1;
  }
#undef STG_P
}

// ---------------------------------------------------------------------------
// Merged Q/K/V/Wot: four M=8192,N=256,K=512 GEMMs as z-slices (pipelined).
// ---------------------------------------------------------------------------
__global__ __launch_bounds__(256, 2)
void gemm_qkvw(const u16* __restrict__ Xri, const u16* __restrict__ Fm,
               const u16* __restrict__ qwb, const u16* __restrict__ kwb,
               const u16* __restrict__ vwb, const u16* __restrict__ owb,
               u16* __restrict__ Qb, u16* __restrict__ Kb,
               u16* __restrict__ Vt, u16* __restrict__ Wot)
{
  constexpr int N = 256, K = 512;
  __shared__ u16 As[2 * 128 * 64] __attribute__((aligned(16)));
  __shared__ u16 Bs[2 * 128 * 64] __attribute__((aligned(16)));

  const int tid  = threadIdx.x;
  const int wave = tid >> 6, lane = tid & 63;
  const int quad = lane >> 4, l15 = lane & 15;
  const int wm = wave >> 1, wn = wave & 1;
  const int m0 = blockIdx.y * 128, n0 = blockIdx.x * 128;
  const int z  = blockIdx.z;

  const u16* Ab = (z == 3) ? Fm : Xri;
  const u16* Bb = (z == 0) ? qwb : (z == 1) ? kwb : (z == 2) ? vwb : owb;
  const float alpha = (z == 3) ? (2.f / 8192.f) : 1.f;

  f32x4 acc[4][4] = {};
  kloop_p(Ab, Bb, K, m0, n0, 0, K, tid, As, Bs, acc);

  #pragma unroll
  for (int i = 0; i < 4; ++i) {
    #pragma unroll
    for (int j = 0; j < 4; ++j) {
      f32x4 v = acc[i][j];
      const int rb = m0 + wm * 64 + i * 16 + quad * 4;
      const int cc = n0 + wn * 64 + j * 16 + l15;
      if (z == 2) {
        const int bb = rb >> 11, ml = rb & 2047;
        union { u16 h[4]; uint2 q; } pk;
        #pragma unroll
        for (int r = 0; r < 4; ++r) pk.h[r] = f2bf(v[r]);
        *(uint2*)&Vt[((size_t)(bb << 8) + cc) * 2048 + ml] = pk.q;
      } else {
        u16* C = (z == 0) ? Qb : (z == 1) ? Kb : Wot;
        #pragma unroll
        for (int r = 0; r < 4; ++r)
          C[(size_t)(rb + r) * N + cc] = f2bf(v[r] * alpha);
      }
    }
  }
}

// ---------------------------------------------------------------------------
// G4: S[b] = (q k^T) .* decay-weight,  upper-triangular blocks only (pipelined).
// ---------------------------------------------------------------------------
__global__ __launch_bounds__(256, 2)
void gemm_g4(const u16* __restrict__ Qb, const u16* __restrict__ Kb,
             u16* __restrict__ S, const float* __restrict__ dl)
{
  if (blockIdx.x < blockIdx.y) return;
  constexpr int N = 2048, K = 256;
  __shared__ u16 As[2 * 128 * 64] __attribute__((aligned(16)));
  __shared__ u16 Bs[2 * 128 * 64] __attribute__((aligned(16)));

  const int tid  = threadIdx.x;
  const int wave = tid >> 6, lane = tid & 63;
  const int quad = lane >> 4, l15 = lane & 15;
  const int wm = wave >> 1, wn = wave & 1;
  const int m0 = blockIdx.y * 128, n0 = blockIdx.x * 128;
  const int z  = blockIdx.z;

  const u16* Ab = Qb + (size_t)z * 2048 * 256;
  const u16* Bb = Kb + (size_t)z * 2048 * 256;

  f32x4 acc[4][4] = {};
  kloop_p(Ab, Bb, K, m0, n0, 0, K, tid, As, Bs, acc);

  const float logit = *dl;
  const float dec = 1.f / (1.f + expf(-logit));
  const float dec_l2 = log2f(dec);
  u16* C = S + (size_t)z * 2048 * 2048;

  #pragma unroll
  for (int i = 0; i < 4; ++i) {
    #pragma unroll
    for (int j = 0; j < 4; ++j) {
      f32x4 v = acc[i][j];
      const int rb = m0 + wm * 64 + i * 16 + quad * 4;
      const int cc = n0 + wn * 64 + j * 16 + l15;
      #pragma unroll
      for (int r = 0; r < 4; ++r) {
        const int d = cc - (rb + r);            // s - t
        float w = (d > 0) ? exp2f(dec_l2 * (float)(d - 1)) : 0.f;
        C[(size_t)(rb + r) * N + cc] = f2bf(v[r] * w);
      }
    }
  }
}

// ---------------------------------------------------------------------------
// G5: R partials = S[b] @ Vt[b], trapezoidal K + split-K=2 (pipelined).
// ---------------------------------------------------------------------------
__global__ __launch_bounds__(256, 2)
void gemm_g5(const u16* __restrict__ S, const u16* __restrict__ Vt,
             float* __restrict__ P5)
{
  constexpr int N = 256, K = 2048;
  __shared__ u16 As[2 * 128 * 64] __attribute__((aligned(16)));
  __shared__ u16 Bs[2 * 128 * 64] __attribute__((aligned(16)));

  const int tid  = threadIdx.x;
  const int wave = tid >> 6, lane = tid & 63;
  const int quad = lane >> 4, l15 = lane & 15;
  const int wm = wave >> 1, wn = wave & 1;
  const int m0 = blockIdx.y * 128, n0 = blockIdx.x * 128;
  const int batch = blockIdx.z & 3, half = blockIdx.z >> 2;

  const u16* Ab = S  + (size_t)batch * 2048 * 2048;
  const u16* Bb = Vt + (size_t)batch * 256 * 2048;

  int kbeg = half * 1024;
  if (m0 > kbeg) kbeg = m0;          // S[t,s]==0 for s<=t
  const int kend = half * 1024 + 1024;

  f32x4 acc[4][4] = {};
  if (kbeg < kend)
    kloop_p(Ab, Bb, K, m0, n0, kbeg, kend, tid, As, Bs, acc);

  float* Pz = P5 + (size_t)half * (8192L * 256) + (size_t)batch * 2048 * 256;
  #pragma unroll
  for (int i = 0; i < 4; ++i) {
    #pragma unroll
    for (int j = 0; j < 4; ++j) {
      const int rb = m0 + wm * 64 + i * 16 + quad * 4;
      const int cc = n0 + wn * 64 + j * 16 + l15;
      #pragma unroll
      for (int r = 0; r < 4; ++r)
        Pz[(size_t)(rb + r) * N + cc] = acc[i][j][r];
    }
  }
}

// ---------------------------------------------------------------------------
// G6: out = (R @ Wot^T) * out_scale,  M=N=8192 K=256, fp32 out (pipelined).
// ---------------------------------------------------------------------------
__global__ __launch_bounds__(256, 2)
void gemm_g6(const u16* __restrict__ R, const u16* __restrict__ Wot,
             float* __restrict__ out, const float* __restrict__ os)
{
  constexpr int N = 8192, K = 256;
  __shared__ u16 As[2 * 128 * 64] __attribute__((aligned(16)));
  __shared__ u16 Bs[2 * 128 * 64] __attribute__((aligned(16)));

  const int tid  = threadIdx.x;
  const int wave = tid >> 6, lane = tid & 63;
  const int quad = lane >> 4, l15 = lane & 15;
  const int wm = wave >> 1, wn = wave & 1;
  const int m0 = blockIdx.y * 128, n0 = blockIdx.x * 128;

  f32x4 acc[4][4] = {};
  kloop_p(R, Wot, K, m0, n0, 0, K, tid, As, Bs, acc);

  const float oscale = *os;
  #pragma unroll
  for (int i = 0; i < 4; ++i) {
    #pragma unroll
    for (int j = 0; j < 4; ++j) {
      const int rb = m0 + wm * 64 + i * 16 + quad * 4;
      const int cc = n0 + wn * 64 + j * 16 + l15;
      #pragma unroll
      for (int r = 0; r < 4; ++r)
        out[(size_t)(rb + r) * N + cc] = acc[i][j][r] * oscale;
    }
  }
}

// F tables: exact integer phase reduction (n*k mod 8192) before trig.
__global__ void genF_row(u16* Fm) {           // Fm [8192][512], coalesced in j
  int idx = blockIdx.x * 256 + threadIdx.x;
  int n = idx >> 9, j = idx & 511;
  int k = (j & 255) + 1;
  int ph = (n * k) & 8191;
  float ang = (float)ph * 7.66990393942820795e-4f;  // 2*pi/8192
  float s, c; sincosf(ang, &s, &c);
  Fm[idx] = f2bf(j < 256 ? c : -s);
}
__global__ void genF_col(u16* Ft) {           // Ft [512][8192], coalesced in n
  int idx = blockIdx.x * 256 + threadIdx.x;
  int j = idx >> 13, n = idx & 8191;
  int k = (j & 255) + 1;
  int ph = (n * k) & 8191;
  float ang = (float)ph * 7.66990393942820795e-4f;
  float s, c; sincosf(ang, &s, &c);
  Ft[idx] = f2bf(j < 256 ? c : -s);
}

__global__ void cast_w4(const float* a, const float* b, const float* c, const float* d,
                        u16* oa, u16* ob, u16* oc, u16* od) {
  int i = blockIdx.x * 256 + threadIdx.x;     // 131072 each
  oa[i] = f2bf(a[i]); ob[i] = f2bf(b[i]); oc[i] = f2bf(c[i]); od[i] = f2bf(d[i]);
}

extern "C" void kernel_launch(void* const* d_in, const int* in_sizes, int n_in,
                              void* d_out, int out_size, void* d_ws, size_t ws_size,
                              hipStream_t stream)
{
  const float* x  = (const float*)d_in[0];
  const float* qw = (const float*)d_in[1];
  const float* kw = (const float*)d_in[2];
  const float* vw = (const float*)d_in[3];
  const float* ow = (const float*)d_in[4];
  const float* dl = (const float*)d_in[5];   // decay_logit
  const float* os = (const float*)d_in[6];   // out_scale
  float* out = (float*)d_out;

  char* W = (char*)d_ws;
  const size_t MB = 1024 * 1024;
  u16* Fm  = (u16*)(W);             // [8192][512]   8 MB   (dead after qkvw)
  u16* Ft  = (u16*)(W + 8 * MB);    // [512][8192]   8 MB   (dead after G1)
  u16* Xri = (u16*)(W + 16 * MB);   // [8192][512]   8 MB
  u16* Qb  = (u16*)(W + 24 * MB);   // [8192][256]   4 MB
  u16* Kb  = (u16*)(W + 28 * MB);   // [8192][256]   4 MB
  u16* Vt  = (u16*)(W + 32 * MB);   // [4][256][2048] 4 MB
  u16* Wot = (u16*)(W + 36 * MB);   // [8192][256]   4 MB
  u16* S   = (u16*)(W + 40 * MB);   // [4][2048][2048] 32 MB (aliases P; P dead before G4)
  float* P = (float*)(W + 40 * MB); // [2][8192][512] fp32 32 MB G1 split-K partials
  float* P5 = (float*)(W);          // [2][8192][256] fp32 16 MB G5 partials (over Fm/Ft, dead)
  u16* R   = (u16*)(W + 72 * MB);   // [8192][256]   4 MB
  u16* qwb = (u16*)(W + 76 * MB);   // 4 x 256 KB
  u16* kwb = qwb + 131072;
  u16* vwb = kwb + 131072;
  u16* owb = vwb + 131072;

  genF_row<<<8192 * 512 / 256, 256, 0, stream>>>(Fm);
  genF_col<<<8192 * 512 / 256, 256, 0, stream>>>(Ft);
  cast_w4<<<131072 / 256, 256, 0, stream>>>(qw, kw, vw, ow, qwb, kwb, vwb, owb);

  // G1: Xri = x @ F   M=8192 N=512 K=8192 (A fp32) -> fp32 partials, reduce
  gemm_g1<<<512, 256, 0, stream>>>(x, Ft, P);
  reduce_cast<<<4096, 256, 0, stream>>>(P, Xri, 8192 * 512 / 4);

  // G2+G3 merged: q, k, v = Xri @ w^T ; Wot = (2/V) * Fm @ ow^T
  gemm_qkvw<<<dim3(2, 64, 4), 256, 0, stream>>>(Xri, Fm, qwb, kwb, vwb, owb,
                                                Qb, Kb, Vt, Wot);

  // G4: S[b] = (q k^T) .* weight, upper-tri blocks only
  gemm_g4<<<dim3(16, 16, 4), 256, 0, stream>>>(Qb, Kb, S, dl);

  // G5: R[b] = S[b] @ v[b], trapezoidal K + split-K=2 -> partials, reduce
  gemm_g5<<<dim3(2, 16, 8), 256, 0, stream>>>(S, Vt, P5);
  reduce_cast<<<2048, 256, 0, stream>>>(P5, R, 8192 * 256 / 4);

  // G6: out = (R @ Wot^T) * out_scale
  gemm_g6<<<dim3(64, 64, 1), 256, 0, stream>>>(R, Wot, out, os);
}